// Round 1
// baseline (414.833 us; speedup 1.0000x reference)
//
#include <hip/hip_runtime.h>

#define NN 10000
#define EE 65536

// ---------------- CSR build ----------------

__global__ void k_hist(const int* __restrict__ dst, int* __restrict__ cnt){
  int e = blockIdx.x*256 + threadIdx.x;
  if(e < EE) atomicAdd(&cnt[dst[e]], 1);
}

__global__ void k_scan(const int* __restrict__ cnt, int* __restrict__ offs, int* __restrict__ cursor){
  __shared__ int buf[1024];
  __shared__ int carry;
  int tid = threadIdx.x;
  if(tid==0) carry = 0;
  __syncthreads();
  for(int base=0; base<NN; base+=1024){
    int i = base + tid;
    int v = (i<NN)? cnt[i] : 0;
    buf[tid] = v;
    __syncthreads();
    for(int o=1;o<1024;o<<=1){
      int tval = (tid>=o)? buf[tid-o] : 0;
      __syncthreads();
      buf[tid] += tval;
      __syncthreads();
    }
    if(i<NN){ int excl = carry + buf[tid] - v; offs[i]=excl; cursor[i]=excl; }
    __syncthreads();
    if(tid==0) carry += buf[1023];
    __syncthreads();
  }
  if(tid==0) offs[NN] = carry;
}

__global__ void k_scatter(const int* __restrict__ dst, int* __restrict__ cursor, int* __restrict__ elist){
  int e = blockIdx.x*256 + threadIdx.x;
  if(e < EE){ int p = atomicAdd(&cursor[dst[e]], 1); elist[p] = e; }
}

// ---------------- weight permute: Bp[(m*cin+i)*64+o] = w2[m, i*64+o] ----------------

__global__ void k_permB(const float* __restrict__ w2, float* __restrict__ Bp, int cin){
  int idx = blockIdx.x*256 + threadIdx.x;
  int total = 64*cin*64;
  if(idx < total){
    int o = idx & 63;
    int tt = idx >> 6;
    int i = tt % cin;
    int m = tt / cin;
    Bp[idx] = w2[(size_t)m*(cin*64) + i*64 + o];
  }
}

// ---------------- edge MLP first layer: h[e,m] = relu(ea[e]@w1 + b1) ----------------

__global__ void k_edge_mlp(const float* __restrict__ ea, const float* __restrict__ w1,
                           const float* __restrict__ b1, float* __restrict__ h){
  int idx = blockIdx.x*256 + threadIdx.x;
  if(idx < EE*64){
    int m = idx & 63;
    int e = idx >> 6;
    const float* a = ea + (size_t)e*4;
    float acc = b1[m] + a[0]*w1[m] + a[1]*w1[64+m] + a[2]*w1[128+m] + a[3]*w1[192+m];
    h[idx] = fmaxf(acc, 0.f);
  }
}

// ---------------- per-dst rank-1 accumulation, cin=16 ----------------

__global__ __launch_bounds__(256) void k_accK1(const float* __restrict__ x, const int* __restrict__ src,
    const int* __restrict__ offs, const int* __restrict__ elist, const float* __restrict__ h,
    float* __restrict__ K, float* __restrict__ XS, int v0){
  int v = v0 + blockIdx.x;
  int t = threadIdx.x;
  int m = t >> 2;            // 0..63
  int ib = (t & 3) << 2;     // 0,4,8,12
  float a0=0.f,a1=0.f,a2=0.f,a3=0.f, xs=0.f;
  __shared__ float sh[64];
  __shared__ float sx[16];
  int p0 = offs[v], p1 = offs[v+1];
  for(int p=p0;p<p1;p++){
    int e = elist[p];
    __syncthreads();
    if(t < 64) sh[t] = h[(size_t)e*64 + t];
    else if(t < 80) sx[t-64] = x[(size_t)src[e]*16 + (t-64)];
    __syncthreads();
    float hm = sh[m];
    a0 += hm*sx[ib]; a1 += hm*sx[ib+1]; a2 += hm*sx[ib+2]; a3 += hm*sx[ib+3];
    if(t<16) xs += sx[t];
  }
  float* Kv = K + (size_t)blockIdx.x*1024 + m*16 + ib;
  *(float4*)Kv = make_float4(a0,a1,a2,a3);
  if(t<16) XS[(size_t)v*64 + t] = xs;
}

// ---------------- per-dst rank-1 accumulation, cin=64 ----------------

__global__ __launch_bounds__(256) void k_accK2(const float* __restrict__ x1, const int* __restrict__ src,
    const int* __restrict__ offs, const int* __restrict__ elist, const float* __restrict__ h,
    float* __restrict__ K, float* __restrict__ XS, int v0){
  int v = v0 + blockIdx.x;
  int t = threadIdx.x;
  int m = t >> 2;            // 0..63
  int ib = (t & 3) << 4;     // 0,16,32,48
  float acc[16];
  #pragma unroll
  for(int j=0;j<16;j++) acc[j]=0.f;
  float xs = 0.f;
  __shared__ float sh[64];
  __shared__ float sx[64];
  int p0 = offs[v], p1 = offs[v+1];
  for(int p=p0;p<p1;p++){
    int e = elist[p];
    __syncthreads();
    if(t < 64) sh[t] = h[(size_t)e*64 + t];
    else if(t < 128) sx[t-64] = x1[(size_t)src[e]*64 + (t-64)];
    __syncthreads();
    float hm = sh[m];
    #pragma unroll
    for(int j=0;j<16;j++) acc[j] += hm * sx[ib+j];
    if(t<64) xs += sx[t];
  }
  float* Kv = K + (size_t)blockIdx.x*4096 + m*64 + ib;
  #pragma unroll
  for(int q=0;q<4;q++)
    *(float4*)(Kv + 4*q) = make_float4(acc[4*q],acc[4*q+1],acc[4*q+2],acc[4*q+3]);
  if(t<64) XS[(size_t)v*64 + t] = xs;
}

// ---------------- split-K GEMM: P[sz][rows][64] = A[rows,k-range] @ B[k-range,64] ----------------
// block tile 128 rows x 64 cols, 256 threads, 8x4 acc per thread.
// As transposed [k][r] with stride 129 (odd -> <=2-way bank conflicts);
// Bs [k][c] stride 68 (float4-aligned rows, 2-way read conflicts).

__global__ __launch_bounds__(256) void k_gemm(const float* __restrict__ A, const float* __restrict__ B,
                                              float* __restrict__ P, int rows, int Ktot, int Kc){
  __shared__ float As[64*129];
  __shared__ float Bs[64*68];
  int t = threadIdx.x;
  int row0 = blockIdx.x*128;
  int k0 = blockIdx.y*Kc;
  int c0 = (t & 15) << 2;        // 0..60
  int r0a = (t >> 4) << 2;       // 0..60
  float acc[8][4];
  #pragma unroll
  for(int i=0;i<8;i++)
    #pragma unroll
    for(int j=0;j<4;j++) acc[i][j]=0.f;

  for(int kk=0; kk<Kc; kk+=64){
    __syncthreads();
    // stage A tile 128x64 (transposed)
    #pragma unroll
    for(int q=0;q<8;q++){
      int r = 16*q + (t>>4);
      int k4 = (t&15)<<2;
      int gr = row0 + r;
      float4 val = make_float4(0.f,0.f,0.f,0.f);
      if(gr < rows) val = *(const float4*)(A + (size_t)gr*Ktot + (k0+kk+k4));
      As[(k4+0)*129 + r] = val.x;
      As[(k4+1)*129 + r] = val.y;
      As[(k4+2)*129 + r] = val.z;
      As[(k4+3)*129 + r] = val.w;
    }
    // stage B tile 64x64
    {
      int k = t>>2;
      int cc = (t&3)<<4;
      #pragma unroll
      for(int q=0;q<4;q++){
        *(float4*)&Bs[k*68 + cc + 4*q] = *(const float4*)(B + (size_t)(k0+kk+k)*64 + cc + 4*q);
      }
    }
    __syncthreads();
    #pragma unroll 4
    for(int k=0;k<64;k++){
      float4 bv = *(float4*)&Bs[k*68 + c0];
      const float* Ar = &As[k*129];
      #pragma unroll
      for(int i=0;i<4;i++){
        float av = Ar[r0a+i];
        acc[i][0] += av*bv.x; acc[i][1] += av*bv.y; acc[i][2] += av*bv.z; acc[i][3] += av*bv.w;
      }
      #pragma unroll
      for(int i=0;i<4;i++){
        float av = Ar[64+r0a+i];
        acc[4+i][0] += av*bv.x; acc[4+i][1] += av*bv.y; acc[4+i][2] += av*bv.z; acc[4+i][3] += av*bv.w;
      }
    }
  }
  size_t base = (size_t)blockIdx.y*rows*64;
  #pragma unroll
  for(int i=0;i<8;i++){
    int r = (i<4)? (r0a+i) : (64 + r0a + (i-4));
    int gr = row0 + r;
    if(gr < rows){
      *(float4*)(P + base + (size_t)gr*64 + c0) = make_float4(acc[i][0],acc[i][1],acc[i][2],acc[i][3]);
    }
  }
}

// ---------------- split reduction + epilogue (mean, bias-term, root, bias, relu) ----------------

__global__ void k_reduce_ep(const float* __restrict__ P, int split, int rows, int v0,
    const float* __restrict__ XS, const float* __restrict__ b2, const float* __restrict__ xprev, int cin,
    const float* __restrict__ root, const float* __restrict__ bias, const int* __restrict__ offs,
    float* __restrict__ out){
  int idx = blockIdx.x*256 + threadIdx.x;
  if(idx >= rows*64) return;
  int r = idx >> 6, o = idx & 63;
  int v = v0 + r;
  float s = 0.f;
  for(int z=0; z<split; z++) s += P[((size_t)z*rows + r)*64 + o];
  float xb = 0.f, rt = 0.f;
  for(int i=0;i<cin;i++){
    xb += XS[(size_t)v*64 + i] * b2[i*64 + o];
    rt += xprev[(size_t)v*cin + i] * root[i*64 + o];
  }
  float c = (float)(offs[v+1]-offs[v]); c = fmaxf(c, 1.f);
  float val = (s + xb)/c + rt + bias[o];
  out[(size_t)v*64 + o] = fmaxf(val, 0.f);
}

// ---------------- readout MLP ----------------

__global__ void k_readout(const float* __restrict__ x2, const float* __restrict__ lw1,
                          const float* __restrict__ lb1, const float* __restrict__ lw2,
                          const float* __restrict__ lb2, float* __restrict__ out){
  int v = blockIdx.x*256 + threadIdx.x;
  if(v >= NN) return;
  float accj[8];
  #pragma unroll
  for(int j=0;j<8;j++) accj[j] = lb1[j];
  const float* xr = x2 + (size_t)v*64;
  #pragma unroll 16
  for(int i=0;i<64;i++){
    float xv = xr[i];
    #pragma unroll
    for(int j=0;j<8;j++) accj[j] += xv*lw1[i*8+j];
  }
  float o = lb2[0];
  #pragma unroll
  for(int j=0;j<8;j++) o += fmaxf(accj[j],0.f)*lw2[j];
  out[v] = o;
}

// ---------------- host ----------------

extern "C" void kernel_launch(void* const* d_in, const int* in_sizes, int n_in,
                              void* d_out, int out_size, void* d_ws, size_t ws_size,
                              hipStream_t stream) {
  const float* x      = (const float*)d_in[0];
  const int*   ei     = (const int*)d_in[1];
  const float* ea     = (const float*)d_in[2];
  const float* nn1_w1 = (const float*)d_in[3];
  const float* nn1_b1 = (const float*)d_in[4];
  const float* nn1_w2 = (const float*)d_in[5];
  const float* nn1_b2 = (const float*)d_in[6];
  const float* root1  = (const float*)d_in[7];
  const float* bias1  = (const float*)d_in[8];
  const float* nn2_w1 = (const float*)d_in[9];
  const float* nn2_b1 = (const float*)d_in[10];
  const float* nn2_w2 = (const float*)d_in[11];
  const float* nn2_b2 = (const float*)d_in[12];
  const float* root2  = (const float*)d_in[13];
  const float* bias2  = (const float*)d_in[14];
  const float* lin1_w = (const float*)d_in[15];
  const float* lin1_b = (const float*)d_in[16];
  const float* lin2_w = (const float*)d_in[17];
  const float* lin2_b = (const float*)d_in[18];
  float* out = (float*)d_out;

  const int* srcIdx = ei;        // edge_index[0]
  const int* dstIdx = ei + EE;   // edge_index[1]

  char* w = (char*)d_ws;
  size_t off = 0;
  auto alloc = [&](size_t bytes)->void*{
    void* p = w + off;
    off = (off + bytes + 255) & ~(size_t)255;
    return p;
  };
  int*   cnt    = (int*)  alloc((size_t)NN*4);
  int*   offs   = (int*)  alloc((size_t)(NN+1)*4);
  int*   cursor = (int*)  alloc((size_t)NN*4);
  int*   elist  = (int*)  alloc((size_t)EE*4);
  float* h      = (float*)alloc((size_t)EE*64*4);
  float* XS     = (float*)alloc((size_t)NN*64*4);
  float* x1     = (float*)alloc((size_t)NN*64*4);
  float* x2b    = (float*)alloc((size_t)NN*64*4);
  float* Bp     = (float*)alloc((size_t)4096*64*4);
  size_t fixedBytes = off;
  size_t R = (ws_size > fixedBytes) ? (ws_size - fixedBytes) : 0;
  // layer2 chunk needs C*(4096 + 8*64)*4 bytes; layer1: C*(1024 + 4*64)*4
  long long C2 = (long long)(R / ((4096 + 8*64)*4));
  long long C1 = (long long)(R / ((1024 + 4*64)*4));
  if(C2 > NN) C2 = NN;
  if(C1 > NN) C1 = NN;
  if(C2 < 1) C2 = 1;
  if(C1 < 1) C1 = 1;
  float* Kbuf = (float*)(w + off);

  // CSR by dst
  hipMemsetAsync(cnt, 0, (size_t)NN*4, stream);
  k_hist   <<<(EE+255)/256, 256, 0, stream>>>(dstIdx, cnt);
  k_scan   <<<1, 1024, 0, stream>>>(cnt, offs, cursor);
  k_scatter<<<(EE+255)/256, 256, 0, stream>>>(dstIdx, cursor, elist);

  // ---------- layer 1 (cin=16) ----------
  k_permB   <<<(64*16*64+255)/256, 256, 0, stream>>>(nn1_w2, Bp, 16);
  k_edge_mlp<<<(EE*64+255)/256, 256, 0, stream>>>(ea, nn1_w1, nn1_b1, h);
  for(long long v0=0; v0<NN; v0+=C1){
    int rows = (int)((NN - v0 < C1) ? (NN - v0) : C1);
    float* P = Kbuf + (size_t)C1*1024;
    k_accK1<<<rows, 256, 0, stream>>>(x, srcIdx, offs, elist, h, Kbuf, XS, (int)v0);
    dim3 g((rows+127)/128, 4);
    k_gemm<<<g, 256, 0, stream>>>(Kbuf, Bp, P, rows, 1024, 256);
    k_reduce_ep<<<(rows*64+255)/256, 256, 0, stream>>>(P, 4, rows, (int)v0, XS, nn1_b2, x, 16,
                                                        root1, bias1, offs, x1);
  }

  // ---------- layer 2 (cin=64) ----------
  k_permB   <<<(64*64*64+255)/256, 256, 0, stream>>>(nn2_w2, Bp, 64);
  k_edge_mlp<<<(EE*64+255)/256, 256, 0, stream>>>(ea, nn2_w1, nn2_b1, h);
  for(long long v0=0; v0<NN; v0+=C2){
    int rows = (int)((NN - v0 < C2) ? (NN - v0) : C2);
    float* P = Kbuf + (size_t)C2*4096;
    k_accK2<<<rows, 256, 0, stream>>>(x1, srcIdx, offs, elist, h, Kbuf, XS, (int)v0);
    dim3 g((rows+127)/128, 8);
    k_gemm<<<g, 256, 0, stream>>>(Kbuf, Bp, P, rows, 4096, 512);
    k_reduce_ep<<<(rows*64+255)/256, 256, 0, stream>>>(P, 8, rows, (int)v0, XS, nn2_b2, x1, 64,
                                                        root2, bias2, offs, x2b);
  }

  // ---------- readout ----------
  k_readout<<<(NN+255)/256, 256, 0, stream>>>(x2b, lin1_w, lin1_b, lin2_w, lin2_b, out);
}

// Round 2
// 395.544 us; speedup vs baseline: 1.0488x; 1.0488x over previous
//
#include <hip/hip_runtime.h>

#define NN 10000
#define EE 65536

// ---------------- CSR build ----------------

__global__ void k_hist(const int* __restrict__ dst, int* __restrict__ cnt){
  int e = blockIdx.x*256 + threadIdx.x;
  if(e < EE) atomicAdd(&cnt[dst[e]], 1);
}

__global__ __launch_bounds__(1024) void k_scan(const int* __restrict__ cnt, int* __restrict__ offs, int* __restrict__ cursor){
  const int T = 1024, PER = (NN + T - 1)/T; // 10
  int tid = threadIdx.x;
  int base = tid*PER;
  int local[PER];
  int s = 0;
  #pragma unroll
  for(int j=0;j<PER;j++){
    int i = base+j;
    int v = (i<NN)? cnt[i] : 0;
    local[j] = s;      // exclusive within-thread
    s += v;
  }
  int lane = tid & 63, wv = tid >> 6;   // 16 waves
  int val = s;
  #pragma unroll
  for(int o=1;o<64;o<<=1){
    int u = __shfl_up(val, o, 64);
    if(lane >= o) val += u;
  }
  __shared__ int wsum[16];
  if(lane==63) wsum[wv] = val;
  __syncthreads();
  if(tid==0){
    int acc=0;
    #pragma unroll
    for(int i=0;i<16;i++){ int t2=wsum[i]; wsum[i]=acc; acc+=t2; }
  }
  __syncthreads();
  int thr_excl = wsum[wv] + (val - s);
  #pragma unroll
  for(int j=0;j<PER;j++){
    int i = base+j;
    if(i<NN){ int e = thr_excl + local[j]; offs[i]=e; cursor[i]=e; }
  }
  if(tid == T-1) offs[NN] = thr_excl + s;
}

__global__ void k_scatter(const int* __restrict__ dst, int* __restrict__ cursor, int* __restrict__ elist){
  int e = blockIdx.x*256 + threadIdx.x;
  if(e < EE){ int p = atomicAdd(&cursor[dst[e]], 1); elist[p] = e; }
}

// ---------------- weight permute: Bp[(m*cin+i)*64+o] = w2[m, i*64+o] ----------------

__global__ void k_permB(const float* __restrict__ w2, float* __restrict__ Bp, int cin){
  int idx = blockIdx.x*256 + threadIdx.x;
  int total = 64*cin*64;
  if(idx < total){
    int o = idx & 63;
    int tt = idx >> 6;
    int i = tt % cin;
    int m = tt / cin;
    Bp[idx] = w2[(size_t)m*(cin*64) + i*64 + o];
  }
}

// ---------------- edge MLP first layer: h[e,m] = relu(ea[e]@w1 + b1) ----------------

__global__ void k_edge_mlp(const float* __restrict__ ea, const float* __restrict__ w1,
                           const float* __restrict__ b1, float* __restrict__ h){
  int idx = blockIdx.x*256 + threadIdx.x;
  if(idx < EE*64){
    int m = idx & 63;
    int e = idx >> 6;
    const float* a = ea + (size_t)e*4;
    float acc = b1[m] + a[0]*w1[m] + a[1]*w1[64+m] + a[2]*w1[128+m] + a[3]*w1[192+m];
    h[idx] = fmaxf(acc, 0.f);
  }
}

// ---------------- per-dst rank-1 accumulation, cin=16 ----------------

__global__ __launch_bounds__(256) void k_accK1(const float* __restrict__ x, const int* __restrict__ src,
    const int* __restrict__ offs, const int* __restrict__ elist, const float* __restrict__ h,
    float* __restrict__ K, float* __restrict__ XS, int v0){
  int v = v0 + blockIdx.x;
  int t = threadIdx.x;
  int m = t >> 2;            // 0..63
  int ib = (t & 3) << 2;     // 0,4,8,12
  float a0=0.f,a1=0.f,a2=0.f,a3=0.f, xs=0.f;
  __shared__ float sh[64];
  __shared__ float sx[16];
  int p0 = offs[v], p1 = offs[v+1];
  for(int p=p0;p<p1;p++){
    int e = elist[p];
    __syncthreads();
    if(t < 64) sh[t] = h[(size_t)e*64 + t];
    else if(t < 80) sx[t-64] = x[(size_t)src[e]*16 + (t-64)];
    __syncthreads();
    float hm = sh[m];
    a0 += hm*sx[ib]; a1 += hm*sx[ib+1]; a2 += hm*sx[ib+2]; a3 += hm*sx[ib+3];
    if(t<16) xs += sx[t];
  }
  float* Kv = K + (size_t)blockIdx.x*1024 + m*16 + ib;
  *(float4*)Kv = make_float4(a0,a1,a2,a3);
  if(t<16) XS[(size_t)v*64 + t] = xs;
}

// ---------------- per-dst rank-1 accumulation, cin=64 ----------------

__global__ __launch_bounds__(256) void k_accK2(const float* __restrict__ x1, const int* __restrict__ src,
    const int* __restrict__ offs, const int* __restrict__ elist, const float* __restrict__ h,
    float* __restrict__ K, float* __restrict__ XS, int v0){
  int v = v0 + blockIdx.x;
  int t = threadIdx.x;
  int m = t >> 2;            // 0..63
  int ib = (t & 3) << 4;     // 0,16,32,48
  float acc[16];
  #pragma unroll
  for(int j=0;j<16;j++) acc[j]=0.f;
  float xs = 0.f;
  __shared__ float sh[64];
  __shared__ float sx[64];
  int p0 = offs[v], p1 = offs[v+1];
  for(int p=p0;p<p1;p++){
    int e = elist[p];
    __syncthreads();
    if(t < 64) sh[t] = h[(size_t)e*64 + t];
    else if(t < 128) sx[t-64] = x1[(size_t)src[e]*64 + (t-64)];
    __syncthreads();
    float hm = sh[m];
    #pragma unroll
    for(int j=0;j<16;j++) acc[j] += hm * sx[ib+j];
    if(t<64) xs += sx[t];
  }
  float* Kv = K + (size_t)blockIdx.x*4096 + m*64 + ib;
  #pragma unroll
  for(int q=0;q<4;q++)
    *(float4*)(Kv + 4*q) = make_float4(acc[4*q],acc[4*q+1],acc[4*q+2],acc[4*q+3]);
  if(t<64) XS[(size_t)v*64 + t] = xs;
}

// ---------------- split-K GEMM: P[splits][rows][64] = A[rows,Kc-range] @ B[Kc-range,64] ----------------
// 128x64 block tile, 256 threads, 8x4 acc/thread, BK=32, register double-buffered staging.
// As transposed [k][r] stride 132 (16B aligned, broadcast reads, no read conflicts);
// Bs [k][c] stride 68 (2-way read conflicts = free).

#define BK 32

__global__ __launch_bounds__(256) void k_gemm(const float* __restrict__ A, const float* __restrict__ B,
                                              float* __restrict__ P, int rows, int Ktot, int Kc){
  __shared__ float As[BK*132];
  __shared__ float Bs[BK*68];
  int t = threadIdx.x;
  int row0 = blockIdx.x*128;
  int k0 = blockIdx.y*Kc;

  int srow = t>>3;          // 0..31 -> rows srow+32q
  int sk   = (t&7)<<2;      // 0,4,...,28
  int bk   = t>>3;          // 0..31
  int bc   = (t&7)<<3;      // 0,8,...,56

  int c0  = (t&15)<<2;      // 0..60
  int r0  = (t>>4)<<2;      // 0..60

  float4 areg0, areg1, areg2, areg3, breg0, breg1;
  int T = Kc/BK;

  float acc[8][4];
  #pragma unroll
  for(int i=0;i<8;i++)
    #pragma unroll
    for(int j=0;j<4;j++) acc[i][j]=0.f;

  // load tile 0
  {
    int kk = k0 + sk;
    int g0 = row0+srow, g1 = g0+32, g2 = g0+64, g3 = g0+96;
    areg0 = (g0<rows)? *(const float4*)(A + (size_t)g0*Ktot + kk) : make_float4(0,0,0,0);
    areg1 = (g1<rows)? *(const float4*)(A + (size_t)g1*Ktot + kk) : make_float4(0,0,0,0);
    areg2 = (g2<rows)? *(const float4*)(A + (size_t)g2*Ktot + kk) : make_float4(0,0,0,0);
    areg3 = (g3<rows)? *(const float4*)(A + (size_t)g3*Ktot + kk) : make_float4(0,0,0,0);
    int kb = k0 + bk;
    breg0 = *(const float4*)(B + (size_t)kb*64 + bc);
    breg1 = *(const float4*)(B + (size_t)kb*64 + bc + 4);
  }

  for(int tt=0; tt<T; tt++){
    // store staged regs to LDS
    {
      int r = srow;
      As[(sk+0)*132 + r     ] = areg0.x; As[(sk+1)*132 + r     ] = areg0.y;
      As[(sk+2)*132 + r     ] = areg0.z; As[(sk+3)*132 + r     ] = areg0.w;
      As[(sk+0)*132 + r + 32] = areg1.x; As[(sk+1)*132 + r + 32] = areg1.y;
      As[(sk+2)*132 + r + 32] = areg1.z; As[(sk+3)*132 + r + 32] = areg1.w;
      As[(sk+0)*132 + r + 64] = areg2.x; As[(sk+1)*132 + r + 64] = areg2.y;
      As[(sk+2)*132 + r + 64] = areg2.z; As[(sk+3)*132 + r + 64] = areg2.w;
      As[(sk+0)*132 + r + 96] = areg3.x; As[(sk+1)*132 + r + 96] = areg3.y;
      As[(sk+2)*132 + r + 96] = areg3.z; As[(sk+3)*132 + r + 96] = areg3.w;
      *(float4*)&Bs[bk*68 + bc    ] = breg0;
      *(float4*)&Bs[bk*68 + bc + 4] = breg1;
    }
    __syncthreads();
    // prefetch next tile into regs
    if(tt+1 < T){
      int kk = k0 + (tt+1)*BK + sk;
      int g0 = row0+srow, g1 = g0+32, g2 = g0+64, g3 = g0+96;
      areg0 = (g0<rows)? *(const float4*)(A + (size_t)g0*Ktot + kk) : make_float4(0,0,0,0);
      areg1 = (g1<rows)? *(const float4*)(A + (size_t)g1*Ktot + kk) : make_float4(0,0,0,0);
      areg2 = (g2<rows)? *(const float4*)(A + (size_t)g2*Ktot + kk) : make_float4(0,0,0,0);
      areg3 = (g3<rows)? *(const float4*)(A + (size_t)g3*Ktot + kk) : make_float4(0,0,0,0);
      int kb = k0 + (tt+1)*BK + bk;
      breg0 = *(const float4*)(B + (size_t)kb*64 + bc);
      breg1 = *(const float4*)(B + (size_t)kb*64 + bc + 4);
    }
    // compute on LDS tile
    #pragma unroll
    for(int k=0;k<BK;k++){
      float4 bv = *(float4*)&Bs[k*68 + c0];
      float4 a0 = *(float4*)&As[k*132 + r0];
      float4 a1 = *(float4*)&As[k*132 + r0 + 64];
      acc[0][0] += a0.x*bv.x; acc[0][1] += a0.x*bv.y; acc[0][2] += a0.x*bv.z; acc[0][3] += a0.x*bv.w;
      acc[1][0] += a0.y*bv.x; acc[1][1] += a0.y*bv.y; acc[1][2] += a0.y*bv.z; acc[1][3] += a0.y*bv.w;
      acc[2][0] += a0.z*bv.x; acc[2][1] += a0.z*bv.y; acc[2][2] += a0.z*bv.z; acc[2][3] += a0.z*bv.w;
      acc[3][0] += a0.w*bv.x; acc[3][1] += a0.w*bv.y; acc[3][2] += a0.w*bv.z; acc[3][3] += a0.w*bv.w;
      acc[4][0] += a1.x*bv.x; acc[4][1] += a1.x*bv.y; acc[4][2] += a1.x*bv.z; acc[4][3] += a1.x*bv.w;
      acc[5][0] += a1.y*bv.x; acc[5][1] += a1.y*bv.y; acc[5][2] += a1.y*bv.z; acc[5][3] += a1.y*bv.w;
      acc[6][0] += a1.z*bv.x; acc[6][1] += a1.z*bv.y; acc[6][2] += a1.z*bv.z; acc[6][3] += a1.z*bv.w;
      acc[7][0] += a1.w*bv.x; acc[7][1] += a1.w*bv.y; acc[7][2] += a1.w*bv.z; acc[7][3] += a1.w*bv.w;
    }
    __syncthreads();
  }

  size_t base = (size_t)blockIdx.y*rows*64;
  #pragma unroll
  for(int i=0;i<4;i++){
    int gr = row0 + r0 + i;
    if(gr < rows)
      *(float4*)(P + base + (size_t)gr*64 + c0) = make_float4(acc[i][0],acc[i][1],acc[i][2],acc[i][3]);
    int gr2 = row0 + 64 + r0 + i;
    if(gr2 < rows)
      *(float4*)(P + base + (size_t)gr2*64 + c0) = make_float4(acc[4+i][0],acc[4+i][1],acc[4+i][2],acc[4+i][3]);
  }
}

// ---------------- split reduction + epilogue (mean, bias-term, root, bias, relu) ----------------

__global__ void k_reduce_ep(const float* __restrict__ P, int split, int rows, int v0,
    const float* __restrict__ XS, const float* __restrict__ b2, const float* __restrict__ xprev, int cin,
    const float* __restrict__ root, const float* __restrict__ bias, const int* __restrict__ offs,
    float* __restrict__ out){
  int idx = blockIdx.x*256 + threadIdx.x;
  if(idx >= rows*64) return;
  int r = idx >> 6, o = idx & 63;
  int v = v0 + r;
  float s = 0.f;
  for(int z=0; z<split; z++) s += P[((size_t)z*rows + r)*64 + o];
  float xb = 0.f, rt = 0.f;
  for(int i=0;i<cin;i++){
    xb += XS[(size_t)v*64 + i] * b2[i*64 + o];
    rt += xprev[(size_t)v*cin + i] * root[i*64 + o];
  }
  float c = (float)(offs[v+1]-offs[v]); c = fmaxf(c, 1.f);
  float val = (s + xb)/c + rt + bias[o];
  out[(size_t)v*64 + o] = fmaxf(val, 0.f);
}

// ---------------- readout MLP ----------------

__global__ void k_readout(const float* __restrict__ x2, const float* __restrict__ lw1,
                          const float* __restrict__ lb1, const float* __restrict__ lw2,
                          const float* __restrict__ lb2, float* __restrict__ out){
  int v = blockIdx.x*256 + threadIdx.x;
  if(v >= NN) return;
  float accj[8];
  #pragma unroll
  for(int j=0;j<8;j++) accj[j] = lb1[j];
  const float* xr = x2 + (size_t)v*64;
  #pragma unroll 16
  for(int i=0;i<64;i++){
    float xv = xr[i];
    #pragma unroll
    for(int j=0;j<8;j++) accj[j] += xv*lw1[i*8+j];
  }
  float o = lb2[0];
  #pragma unroll
  for(int j=0;j<8;j++) o += fmaxf(accj[j],0.f)*lw2[j];
  out[v] = o;
}

// ---------------- host ----------------

extern "C" void kernel_launch(void* const* d_in, const int* in_sizes, int n_in,
                              void* d_out, int out_size, void* d_ws, size_t ws_size,
                              hipStream_t stream) {
  const float* x      = (const float*)d_in[0];
  const int*   ei     = (const int*)d_in[1];
  const float* ea     = (const float*)d_in[2];
  const float* nn1_w1 = (const float*)d_in[3];
  const float* nn1_b1 = (const float*)d_in[4];
  const float* nn1_w2 = (const float*)d_in[5];
  const float* nn1_b2 = (const float*)d_in[6];
  const float* root1  = (const float*)d_in[7];
  const float* bias1  = (const float*)d_in[8];
  const float* nn2_w1 = (const float*)d_in[9];
  const float* nn2_b1 = (const float*)d_in[10];
  const float* nn2_w2 = (const float*)d_in[11];
  const float* nn2_b2 = (const float*)d_in[12];
  const float* root2  = (const float*)d_in[13];
  const float* bias2  = (const float*)d_in[14];
  const float* lin1_w = (const float*)d_in[15];
  const float* lin1_b = (const float*)d_in[16];
  const float* lin2_w = (const float*)d_in[17];
  const float* lin2_b = (const float*)d_in[18];
  float* out = (float*)d_out;

  const int* srcIdx = ei;        // edge_index[0]
  const int* dstIdx = ei + EE;   // edge_index[1]

  char* w = (char*)d_ws;
  size_t off = 0;
  auto alloc = [&](size_t bytes)->void*{
    void* p = w + off;
    off = (off + bytes + 255) & ~(size_t)255;
    return p;
  };
  int*   cnt    = (int*)  alloc((size_t)NN*4);
  int*   offs   = (int*)  alloc((size_t)(NN+1)*4);
  int*   cursor = (int*)  alloc((size_t)NN*4);
  int*   elist  = (int*)  alloc((size_t)EE*4);
  float* h      = (float*)alloc((size_t)EE*64*4);
  float* XS     = (float*)alloc((size_t)NN*64*4);
  float* x1     = (float*)alloc((size_t)NN*64*4);
  float* x2b    = (float*)alloc((size_t)NN*64*4);
  float* Bp     = (float*)alloc((size_t)4096*64*4);
  size_t fixedBytes = off;
  size_t R = (ws_size > fixedBytes) ? (ws_size - fixedBytes) : 0;
  long long C2 = (long long)(R / ((4096 + 8*64)*4));
  long long C1 = (long long)(R / ((1024 + 4*64)*4));
  if(C2 > NN) C2 = NN;
  if(C1 > NN) C1 = NN;
  if(C2 < 1) C2 = 1;
  if(C1 < 1) C1 = 1;
  float* Kbuf = (float*)(w + off);

  // CSR by dst
  hipMemsetAsync(cnt, 0, (size_t)NN*4, stream);
  k_hist   <<<(EE+255)/256, 256, 0, stream>>>(dstIdx, cnt);
  k_scan   <<<1, 1024, 0, stream>>>(cnt, offs, cursor);
  k_scatter<<<(EE+255)/256, 256, 0, stream>>>(dstIdx, cursor, elist);

  // ---------- layer 1 (cin=16) ----------
  k_permB   <<<(64*16*64+255)/256, 256, 0, stream>>>(nn1_w2, Bp, 16);
  k_edge_mlp<<<(EE*64+255)/256, 256, 0, stream>>>(ea, nn1_w1, nn1_b1, h);
  for(long long v0=0; v0<NN; v0+=C1){
    int rows = (int)((NN - v0 < C1) ? (NN - v0) : C1);
    float* P = Kbuf + (size_t)C1*1024;
    k_accK1<<<rows, 256, 0, stream>>>(x, srcIdx, offs, elist, h, Kbuf, XS, (int)v0);
    dim3 g((rows+127)/128, 4);
    k_gemm<<<g, 256, 0, stream>>>(Kbuf, Bp, P, rows, 1024, 256);
    k_reduce_ep<<<(rows*64+255)/256, 256, 0, stream>>>(P, 4, rows, (int)v0, XS, nn1_b2, x, 16,
                                                        root1, bias1, offs, x1);
  }

  // ---------- layer 2 (cin=64) ----------
  k_permB   <<<(64*64*64+255)/256, 256, 0, stream>>>(nn2_w2, Bp, 64);
  k_edge_mlp<<<(EE*64+255)/256, 256, 0, stream>>>(ea, nn2_w1, nn2_b1, h);
  for(long long v0=0; v0<NN; v0+=C2){
    int rows = (int)((NN - v0 < C2) ? (NN - v0) : C2);
    float* P = Kbuf + (size_t)C2*4096;
    k_accK2<<<rows, 256, 0, stream>>>(x1, srcIdx, offs, elist, h, Kbuf, XS, (int)v0);
    dim3 g((rows+127)/128, 8);
    k_gemm<<<g, 256, 0, stream>>>(Kbuf, Bp, P, rows, 4096, 512);
    k_reduce_ep<<<(rows*64+255)/256, 256, 0, stream>>>(P, 8, rows, (int)v0, XS, nn2_b2, x1, 64,
                                                        root2, bias2, offs, x2b);
  }

  // ---------- readout ----------
  k_readout<<<(NN+255)/256, 256, 0, stream>>>(x2b, lin1_w, lin1_b, lin2_w, lin2_b, out);
}

// Round 3
// 268.022 us; speedup vs baseline: 1.5478x; 1.4758x over previous
//
#include <hip/hip_runtime.h>
#include <hip/hip_bf16.h>

#define NN 10000
#define EE 65536

using short8  = __attribute__((ext_vector_type(8))) short;
using float4v = __attribute__((ext_vector_type(4))) float;

__device__ __forceinline__ unsigned short f2b(float f){
  union { float f; unsigned int u; } v; v.f = f;
  unsigned int u = v.u;
  unsigned int r = (u + 0x7fff + ((u >> 16) & 1)) >> 16;  // RNE
  return (unsigned short)r;
}

// ---------------- CSR build ----------------

__global__ void k_hist(const int* __restrict__ dst, int* __restrict__ cnt){
  int e = blockIdx.x*256 + threadIdx.x;
  if(e < EE) atomicAdd(&cnt[dst[e]], 1);
}

__global__ __launch_bounds__(1024) void k_scan(const int* __restrict__ cnt, int* __restrict__ offs, int* __restrict__ cursor){
  const int T = 1024, PER = (NN + T - 1)/T; // 10
  int tid = threadIdx.x;
  int base = tid*PER;
  int local[PER];
  int s = 0;
  #pragma unroll
  for(int j=0;j<PER;j++){
    int i = base+j;
    int v = (i<NN)? cnt[i] : 0;
    local[j] = s;
    s += v;
  }
  int lane = tid & 63, wv = tid >> 6;
  int val = s;
  #pragma unroll
  for(int o=1;o<64;o<<=1){
    int u = __shfl_up(val, o, 64);
    if(lane >= o) val += u;
  }
  __shared__ int wsum[16];
  if(lane==63) wsum[wv] = val;
  __syncthreads();
  if(tid==0){
    int acc=0;
    #pragma unroll
    for(int i=0;i<16;i++){ int t2=wsum[i]; wsum[i]=acc; acc+=t2; }
  }
  __syncthreads();
  int thr_excl = wsum[wv] + (val - s);
  #pragma unroll
  for(int j=0;j<PER;j++){
    int i = base+j;
    if(i<NN){ int e = thr_excl + local[j]; offs[i]=e; cursor[i]=e; }
  }
  if(tid == T-1) offs[NN] = thr_excl + s;
}

__global__ void k_scatter(const int* __restrict__ dst, int* __restrict__ cursor, int* __restrict__ elist){
  int e = blockIdx.x*256 + threadIdx.x;
  if(e < EE){ int p = atomicAdd(&cursor[dst[e]], 1); elist[p] = e; }
}

// ---------------- weight permute to bf16, transposed: Bt[o][m*cin+i] = w2[m, i*64+o] ----------------

__global__ void k_permB(const float* __restrict__ w2, unsigned short* __restrict__ Bt, int cin){
  int idx = blockIdx.x*256 + threadIdx.x;
  int K = cin*64;
  int total = 64*K;
  if(idx < total){
    int o = idx / K;
    int k = idx - o*K;
    int m = k / cin;
    int i = k - m*cin;
    Bt[idx] = f2b(w2[(size_t)m*(cin*64) + i*64 + o]);
  }
}

// ---------------- edge MLP first layer: h[e,m] = relu(ea[e]@w1 + b1) ----------------

__global__ void k_edge_mlp(const float* __restrict__ ea, const float* __restrict__ w1,
                           const float* __restrict__ b1, float* __restrict__ h){
  int idx = blockIdx.x*256 + threadIdx.x;
  if(idx < EE*64){
    int m = idx & 63;
    int e = idx >> 6;
    const float* a = ea + (size_t)e*4;
    float acc = b1[m] + a[0]*w1[m] + a[1]*w1[64+m] + a[2]*w1[128+m] + a[3]*w1[192+m];
    h[idx] = fmaxf(acc, 0.f);
  }
}

// ---------------- per-dst rank-1 accumulation, cin=16 (one wave per node) ----------------
// lane L: i = L&15, mg = L>>4; acc over m = mg*16+j.  K1 row layout: k = m*16 + i (bf16).

__global__ __launch_bounds__(64) void k_accK1(const float* __restrict__ x, const int* __restrict__ src,
    const int* __restrict__ offs, const int* __restrict__ elist, const float* __restrict__ h,
    unsigned short* __restrict__ K1, float* __restrict__ XS, int v0){
  int v = v0 + blockIdx.x;
  int L = threadIdx.x;
  int i = L & 15, mg = L >> 4;
  __shared__ float sh[2][64];
  float acc[16];
  #pragma unroll
  for(int j=0;j<16;j++) acc[j]=0.f;
  float xs = 0.f;
  int p0 = offs[v], p1 = offs[v+1];
  float h_nxt = 0.f, x_nxt = 0.f;
  if(p0 < p1){
    int e = elist[p0];
    h_nxt = h[(size_t)e*64 + L];
    x_nxt = x[(size_t)src[e]*16 + i];
  }
  for(int p=p0;p<p1;p++){
    int buf = (p-p0)&1;
    float hv = h_nxt, xv = x_nxt;
    sh[buf][L] = hv;
    __syncthreads();
    if(p+1<p1){
      int e = elist[p+1];
      h_nxt = h[(size_t)e*64 + L];
      x_nxt = x[(size_t)src[e]*16 + i];
    }
    xs += xv;
    #pragma unroll
    for(int j4=0;j4<4;j4++){
      float4 h4 = *(float4*)&sh[buf][mg*16 + j4*4];
      acc[j4*4+0] += h4.x*xv; acc[j4*4+1] += h4.y*xv;
      acc[j4*4+2] += h4.z*xv; acc[j4*4+3] += h4.w*xv;
    }
  }
  unsigned short* Kv = K1 + (size_t)blockIdx.x*1024;
  #pragma unroll
  for(int j=0;j<16;j++) Kv[(mg*16+j)*16 + i] = f2b(acc[j]);
  if(mg==0) XS[(size_t)v*64 + i] = xs;
}

// ---------------- per-dst rank-1 accumulation, cin=64 (one wave per node) ----------------
// lane L owns column i=L; acc[m] over all 64 m.  K row layout: k = m*64 + i (bf16).

__global__ __launch_bounds__(64) void k_accK2(const float* __restrict__ x1, const int* __restrict__ src,
    const int* __restrict__ offs, const int* __restrict__ elist, const float* __restrict__ h,
    unsigned short* __restrict__ K, float* __restrict__ XS, int v0){
  int v = v0 + blockIdx.x;
  int L = threadIdx.x;
  __shared__ float sh[2][64];
  float acc[64];
  #pragma unroll
  for(int m=0;m<64;m++) acc[m]=0.f;
  float xs = 0.f;
  int p0 = offs[v], p1 = offs[v+1];
  float h_nxt = 0.f, x_nxt = 0.f;
  if(p0 < p1){
    int e = elist[p0];
    h_nxt = h[(size_t)e*64 + L];
    x_nxt = x1[(size_t)src[e]*64 + L];
  }
  for(int p=p0;p<p1;p++){
    int buf = (p-p0)&1;
    float hv = h_nxt, xv = x_nxt;
    sh[buf][L] = hv;
    __syncthreads();
    if(p+1<p1){
      int e = elist[p+1];
      h_nxt = h[(size_t)e*64 + L];
      x_nxt = x1[(size_t)src[e]*64 + L];
    }
    xs += xv;
    #pragma unroll
    for(int m4=0;m4<16;m4++){
      float4 h4 = *(float4*)&sh[buf][m4*4];
      acc[m4*4+0] += h4.x*xv; acc[m4*4+1] += h4.y*xv;
      acc[m4*4+2] += h4.z*xv; acc[m4*4+3] += h4.w*xv;
    }
  }
  unsigned short* Kv = K + (size_t)blockIdx.x*4096;
  #pragma unroll
  for(int m=0;m<64;m++) Kv[m*64 + L] = f2b(acc[m]);
  XS[(size_t)v*64 + L] = xs;
}

// ---------------- MFMA split-K GEMM: P[z][rows][64] = A[rows, Kc-slice](bf16) @ Bt^T (bf16) ----------------
// 256 threads = 4 waves; block tile 128 rows x 64 cols; wave w: rows [w*32, w*32+32).
// BK=64 staged per iteration.  As[128][72] bf16 (pad 8 -> 2-way conflicts), Bs[64][72].

#define GBK 64

__global__ __launch_bounds__(256) void k_gemm(const unsigned short* __restrict__ A,
    const unsigned short* __restrict__ Bt, float* __restrict__ P,
    int rows, int Ktot, int Kc){
  __shared__ unsigned short As[128*72];
  __shared__ unsigned short Bs[64*72];
  int t = threadIdx.x;
  int lane = t & 63;
  int w = t >> 6;
  int row0 = blockIdx.x*128;
  int k0 = blockIdx.y*Kc;

  int srow  = t >> 3;        // 0..31
  int skseg = (t & 7) << 3;  // elem 0,8,...,56

  float4v acc[2][4];
  #pragma unroll
  for(int rt=0;rt<2;rt++)
    #pragma unroll
    for(int ct=0;ct<4;ct++)
      #pragma unroll
      for(int q=0;q<4;q++) acc[rt][ct][q]=0.f;

  int lrow = lane & 15;
  int lk   = (lane >> 4) << 3;  // 0,8,16,24

  for(int kk=0; kk<Kc; kk+=GBK){
    __syncthreads();
    // stage A tile: 128 rows x 64 k
    #pragma unroll
    for(int q=0;q<4;q++){
      int r = srow + 32*q;
      int gr = row0 + r;
      short8 val = {0,0,0,0,0,0,0,0};
      if(gr < rows) val = *(const short8*)(A + (size_t)gr*Ktot + k0 + kk + skseg);
      *(short8*)(As + r*72 + skseg) = val;
    }
    // stage Bt tile: 64 o-rows x 64 k
    #pragma unroll
    for(int q=0;q<2;q++){
      int o = srow + 32*q;
      *(short8*)(Bs + o*72 + skseg) = *(const short8*)(Bt + (size_t)o*Ktot + k0 + kk + skseg);
    }
    __syncthreads();
    #pragma unroll
    for(int k32=0;k32<2;k32++){
      int kf = k32*32 + lk;
      short8 a0 = *(short8*)(As + (w*32      + lrow)*72 + kf);
      short8 a1 = *(short8*)(As + (w*32 + 16 + lrow)*72 + kf);
      #pragma unroll
      for(int ct=0;ct<4;ct++){
        short8 b = *(short8*)(Bs + (ct*16 + lrow)*72 + kf);
        acc[0][ct] = __builtin_amdgcn_mfma_f32_16x16x32_bf16(a0, b, acc[0][ct], 0,0,0);
        acc[1][ct] = __builtin_amdgcn_mfma_f32_16x16x32_bf16(a1, b, acc[1][ct], 0,0,0);
      }
    }
  }
  // epilogue: C/D layout col=lane&15, row=(lane>>4)*4+reg
  size_t base = (size_t)blockIdx.y*rows*64;
  int quad = lane >> 4;
  #pragma unroll
  for(int rt=0;rt<2;rt++){
    #pragma unroll
    for(int ct=0;ct<4;ct++){
      int c = ct*16 + lrow;
      #pragma unroll
      for(int reg=0;reg<4;reg++){
        int r = row0 + w*32 + rt*16 + quad*4 + reg;
        if(r < rows) P[base + (size_t)r*64 + c] = acc[rt][ct][reg];
      }
    }
  }
}

// ---------------- split reduction + epilogue (mean, bias-term, root, bias, relu) ----------------

__global__ void k_reduce_ep(const float* __restrict__ P, int split, int rows, int v0,
    const float* __restrict__ XS, const float* __restrict__ b2, const float* __restrict__ xprev, int cin,
    const float* __restrict__ root, const float* __restrict__ bias, const int* __restrict__ offs,
    float* __restrict__ out){
  int idx = blockIdx.x*256 + threadIdx.x;
  if(idx >= rows*64) return;
  int r = idx >> 6, o = idx & 63;
  int v = v0 + r;
  float s = 0.f;
  for(int z=0; z<split; z++) s += P[((size_t)z*rows + r)*64 + o];
  float xb = 0.f, rt = 0.f;
  for(int i=0;i<cin;i++){
    xb += XS[(size_t)v*64 + i] * b2[i*64 + o];
    rt += xprev[(size_t)v*cin + i] * root[i*64 + o];
  }
  float c = (float)(offs[v+1]-offs[v]); c = fmaxf(c, 1.f);
  float val = (s + xb)/c + rt + bias[o];
  out[(size_t)v*64 + o] = fmaxf(val, 0.f);
}

// ---------------- readout MLP ----------------

__global__ void k_readout(const float* __restrict__ x2, const float* __restrict__ lw1,
                          const float* __restrict__ lb1, const float* __restrict__ lw2,
                          const float* __restrict__ lb2, float* __restrict__ out){
  int v = blockIdx.x*256 + threadIdx.x;
  if(v >= NN) return;
  float accj[8];
  #pragma unroll
  for(int j=0;j<8;j++) accj[j] = lb1[j];
  const float* xr = x2 + (size_t)v*64;
  #pragma unroll 16
  for(int i=0;i<64;i++){
    float xv = xr[i];
    #pragma unroll
    for(int j=0;j<8;j++) accj[j] += xv*lw1[i*8+j];
  }
  float o = lb2[0];
  #pragma unroll
  for(int j=0;j<8;j++) o += fmaxf(accj[j],0.f)*lw2[j];
  out[v] = o;
}

// ---------------- host ----------------

extern "C" void kernel_launch(void* const* d_in, const int* in_sizes, int n_in,
                              void* d_out, int out_size, void* d_ws, size_t ws_size,
                              hipStream_t stream) {
  const float* x      = (const float*)d_in[0];
  const int*   ei     = (const int*)d_in[1];
  const float* ea     = (const float*)d_in[2];
  const float* nn1_w1 = (const float*)d_in[3];
  const float* nn1_b1 = (const float*)d_in[4];
  const float* nn1_w2 = (const float*)d_in[5];
  const float* nn1_b2 = (const float*)d_in[6];
  const float* root1  = (const float*)d_in[7];
  const float* bias1  = (const float*)d_in[8];
  const float* nn2_w1 = (const float*)d_in[9];
  const float* nn2_b1 = (const float*)d_in[10];
  const float* nn2_w2 = (const float*)d_in[11];
  const float* nn2_b2 = (const float*)d_in[12];
  const float* root2  = (const float*)d_in[13];
  const float* bias2  = (const float*)d_in[14];
  const float* lin1_w = (const float*)d_in[15];
  const float* lin1_b = (const float*)d_in[16];
  const float* lin2_w = (const float*)d_in[17];
  const float* lin2_b = (const float*)d_in[18];
  float* out = (float*)d_out;

  const int* srcIdx = ei;        // edge_index[0]
  const int* dstIdx = ei + EE;   // edge_index[1]

  char* w = (char*)d_ws;
  size_t off = 0;
  auto alloc = [&](size_t bytes)->void*{
    void* p = w + off;
    off = (off + bytes + 255) & ~(size_t)255;
    return p;
  };
  int*            cnt    = (int*)           alloc((size_t)NN*4);
  int*            offs   = (int*)           alloc((size_t)(NN+1)*4);
  int*            cursor = (int*)           alloc((size_t)NN*4);
  int*            elist  = (int*)           alloc((size_t)EE*4);
  float*          h      = (float*)         alloc((size_t)EE*64*4);
  float*          XS     = (float*)         alloc((size_t)NN*64*4);
  float*          x1     = (float*)         alloc((size_t)NN*64*4);
  float*          x2b    = (float*)         alloc((size_t)NN*64*4);
  unsigned short* Bp     = (unsigned short*)alloc((size_t)4096*64*2);
  size_t fixedBytes = off;
  size_t R = (ws_size > fixedBytes) ? (ws_size - fixedBytes) : 0;

  const int S1 = 8, S2 = 16;
  // per-row bytes: layer2: K 4096*2 + P S2*64*4 ; layer1: K 1024*2 + P S1*64*4
  long long C2max = (long long)(R / (4096*2 + S2*64*4));
  long long C1max = (long long)(R / (1024*2 + S1*64*4));
  if(C2max > NN) C2max = NN;
  if(C1max > NN) C1max = NN;
  if(C2max < 128) C2max = 128;
  if(C1max < 128) C1max = 128;
  int nch2 = (int)((NN + C2max - 1)/C2max);
  int nch1 = (int)((NN + C1max - 1)/C1max);
  long long C2 = (NN + nch2 - 1)/nch2;
  long long C1 = (NN + nch1 - 1)/nch1;

  unsigned short* Kbuf = (unsigned short*)(w + off);

  // CSR by dst
  hipMemsetAsync(cnt, 0, (size_t)NN*4, stream);
  k_hist   <<<(EE+255)/256, 256, 0, stream>>>(dstIdx, cnt);
  k_scan   <<<1, 1024, 0, stream>>>(cnt, offs, cursor);
  k_scatter<<<(EE+255)/256, 256, 0, stream>>>(dstIdx, cursor, elist);

  // ---------- layer 1 (cin=16, Ktot=1024) ----------
  k_permB   <<<(64*16*64+255)/256, 256, 0, stream>>>(nn1_w2, Bp, 16);
  k_edge_mlp<<<(EE*64+255)/256, 256, 0, stream>>>(ea, nn1_w1, nn1_b1, h);
  {
    float* P = (float*)(w + off + (size_t)C1*1024*2);
    for(long long v0=0; v0<NN; v0+=C1){
      int rows = (int)((NN - v0 < C1) ? (NN - v0) : C1);
      k_accK1<<<rows, 64, 0, stream>>>(x, srcIdx, offs, elist, h, Kbuf, XS, (int)v0);
      dim3 g((rows+127)/128, S1);
      k_gemm<<<g, 256, 0, stream>>>(Kbuf, Bp, P, rows, 1024, 1024/S1);
      k_reduce_ep<<<(rows*64+255)/256, 256, 0, stream>>>(P, S1, rows, (int)v0, XS, nn1_b2, x, 16,
                                                          root1, bias1, offs, x1);
    }
  }

  // ---------- layer 2 (cin=64, Ktot=4096) ----------
  k_permB   <<<(64*64*64+255)/256, 256, 0, stream>>>(nn2_w2, Bp, 64);
  k_edge_mlp<<<(EE*64+255)/256, 256, 0, stream>>>(ea, nn2_w1, nn2_b1, h);
  {
    float* P = (float*)(w + off + (size_t)C2*4096*2);
    for(long long v0=0; v0<NN; v0+=C2){
      int rows = (int)((NN - v0 < C2) ? (NN - v0) : C2);
      k_accK2<<<rows, 64, 0, stream>>>(x1, srcIdx, offs, elist, h, Kbuf, XS, (int)v0);
      dim3 g((rows+127)/128, S2);
      k_gemm<<<g, 256, 0, stream>>>(Kbuf, Bp, P, rows, 4096, 4096/S2);
      k_reduce_ep<<<(rows*64+255)/256, 256, 0, stream>>>(P, S2, rows, (int)v0, XS, nn2_b2, x1, 64,
                                                          root2, bias2, offs, x2b);
    }
  }

  // ---------- readout ----------
  k_readout<<<(NN+255)/256, 256, 0, stream>>>(x2b, lin1_w, lin1_b, lin2_w, lin2_b, out);
}

// Round 4
// 240.107 us; speedup vs baseline: 1.7277x; 1.1163x over previous
//
#include <hip/hip_runtime.h>
#include <hip/hip_bf16.h>

#define NN 10000
#define EE 65536

using short8  = __attribute__((ext_vector_type(8))) short;
using float4v = __attribute__((ext_vector_type(4))) float;

__device__ __forceinline__ unsigned short f2b(float f){
  union { float f; unsigned int u; } v; v.f = f;
  unsigned int u = v.u;
  unsigned int r = (u + 0x7fff + ((u >> 16) & 1)) >> 16;  // RNE
  return (unsigned short)r;
}

// ---------------- CSR build ----------------

__global__ void k_hist(const int* __restrict__ dst, int* __restrict__ cnt){
  int e = blockIdx.x*256 + threadIdx.x;
  if(e < EE) atomicAdd(&cnt[dst[e]], 1);
}

__global__ __launch_bounds__(1024) void k_scan(const int* __restrict__ cnt, int* __restrict__ offs, int* __restrict__ cursor){
  const int T = 1024, PER = (NN + T - 1)/T; // 10
  int tid = threadIdx.x;
  int base = tid*PER;
  int local[PER];
  int s = 0;
  #pragma unroll
  for(int j=0;j<PER;j++){
    int i = base+j;
    int v = (i<NN)? cnt[i] : 0;
    local[j] = s;
    s += v;
  }
  int lane = tid & 63, wv = tid >> 6;
  int val = s;
  #pragma unroll
  for(int o=1;o<64;o<<=1){
    int u = __shfl_up(val, o, 64);
    if(lane >= o) val += u;
  }
  __shared__ int wsum[16];
  if(lane==63) wsum[wv] = val;
  __syncthreads();
  if(tid==0){
    int acc=0;
    #pragma unroll
    for(int i=0;i<16;i++){ int t2=wsum[i]; wsum[i]=acc; acc+=t2; }
  }
  __syncthreads();
  int thr_excl = wsum[wv] + (val - s);
  #pragma unroll
  for(int j=0;j<PER;j++){
    int i = base+j;
    if(i<NN){ int e = thr_excl + local[j]; offs[i]=e; cursor[i]=e; }
  }
  if(tid == T-1) offs[NN] = thr_excl + s;
}

__global__ void k_scatter(const int* __restrict__ dst, int* __restrict__ cursor, int* __restrict__ elist){
  int e = blockIdx.x*256 + threadIdx.x;
  if(e < EE){ int p = atomicAdd(&cursor[dst[e]], 1); elist[p] = e; }
}

// ---------------- weight permute to bf16, transposed: Bt[o][m*cin+i] = w2[m, i*64+o] ----------------

__global__ void k_permB(const float* __restrict__ w2, unsigned short* __restrict__ Bt, int cin){
  int idx = blockIdx.x*256 + threadIdx.x;
  int K = cin*64;
  int total = 64*K;
  if(idx < total){
    int o = idx / K;
    int k = idx - o*K;
    int m = k / cin;
    int i = k - m*cin;
    Bt[idx] = f2b(w2[(size_t)m*(cin*64) + i*64 + o]);
  }
}

// ---------------- edge MLP first layer: h[e,m] = relu(ea[e]@w1 + b1) ----------------

__global__ void k_edge_mlp(const float* __restrict__ ea, const float* __restrict__ w1,
                           const float* __restrict__ b1, float* __restrict__ h){
  int idx = blockIdx.x*256 + threadIdx.x;
  if(idx < EE*64){
    int m = idx & 63;
    int e = idx >> 6;
    const float* a = ea + (size_t)e*4;
    float acc = b1[m] + a[0]*w1[m] + a[1]*w1[64+m] + a[2]*w1[128+m] + a[3]*w1[192+m];
    h[idx] = fmaxf(acc, 0.f);
  }
}

// ---------------- per-dst rank-1 accumulation, cin=16 (one wave per node) ----------------

__global__ __launch_bounds__(64) void k_accK1(const float* __restrict__ x, const int* __restrict__ src,
    const int* __restrict__ offs, const int* __restrict__ elist, const float* __restrict__ h,
    unsigned short* __restrict__ K1, float* __restrict__ XS, int v0){
  int v = v0 + blockIdx.x;
  int L = threadIdx.x;
  int i = L & 15, mg = L >> 4;
  __shared__ float sh[2][64];
  float acc[16];
  #pragma unroll
  for(int j=0;j<16;j++) acc[j]=0.f;
  float xs = 0.f;
  int p0 = offs[v], p1 = offs[v+1];
  float h_nxt = 0.f, x_nxt = 0.f;
  if(p0 < p1){
    int e = elist[p0];
    h_nxt = h[(size_t)e*64 + L];
    x_nxt = x[(size_t)src[e]*16 + i];
  }
  for(int p=p0;p<p1;p++){
    int buf = (p-p0)&1;
    float hv = h_nxt, xv = x_nxt;
    sh[buf][L] = hv;
    __syncthreads();
    if(p+1<p1){
      int e = elist[p+1];
      h_nxt = h[(size_t)e*64 + L];
      x_nxt = x[(size_t)src[e]*16 + i];
    }
    xs += xv;
    #pragma unroll
    for(int j4=0;j4<4;j4++){
      float4 h4 = *(float4*)&sh[buf][mg*16 + j4*4];
      acc[j4*4+0] += h4.x*xv; acc[j4*4+1] += h4.y*xv;
      acc[j4*4+2] += h4.z*xv; acc[j4*4+3] += h4.w*xv;
    }
  }
  unsigned short* Kv = K1 + (size_t)blockIdx.x*1024;
  #pragma unroll
  for(int j=0;j<16;j++) Kv[(mg*16+j)*16 + i] = f2b(acc[j]);
  if(mg==0) XS[(size_t)v*64 + i] = xs;
}

// ---------------- per-dst rank-1 accumulation, cin=64 (one wave per node) ----------------

__global__ __launch_bounds__(64) void k_accK2(const float* __restrict__ x1, const int* __restrict__ src,
    const int* __restrict__ offs, const int* __restrict__ elist, const float* __restrict__ h,
    unsigned short* __restrict__ K, float* __restrict__ XS, int v0){
  int v = v0 + blockIdx.x;
  int L = threadIdx.x;
  __shared__ float sh[2][64];
  float acc[64];
  #pragma unroll
  for(int m=0;m<64;m++) acc[m]=0.f;
  float xs = 0.f;
  int p0 = offs[v], p1 = offs[v+1];
  float h_nxt = 0.f, x_nxt = 0.f;
  if(p0 < p1){
    int e = elist[p0];
    h_nxt = h[(size_t)e*64 + L];
    x_nxt = x1[(size_t)src[e]*64 + L];
  }
  for(int p=p0;p<p1;p++){
    int buf = (p-p0)&1;
    float hv = h_nxt, xv = x_nxt;
    sh[buf][L] = hv;
    __syncthreads();
    if(p+1<p1){
      int e = elist[p+1];
      h_nxt = h[(size_t)e*64 + L];
      x_nxt = x1[(size_t)src[e]*64 + L];
    }
    xs += xv;
    #pragma unroll
    for(int m4=0;m4<16;m4++){
      float4 h4 = *(float4*)&sh[buf][m4*4];
      acc[m4*4+0] += h4.x*xv; acc[m4*4+1] += h4.y*xv;
      acc[m4*4+2] += h4.z*xv; acc[m4*4+3] += h4.w*xv;
    }
  }
  unsigned short* Kv = K + (size_t)blockIdx.x*4096;
  #pragma unroll
  for(int m=0;m<64;m++) Kv[m*64 + L] = f2b(acc[m]);
  XS[(size_t)v*64 + L] = xs;
}

// ---------------- MFMA split-K GEMM ----------------

#define GBK 64

__global__ __launch_bounds__(256) void k_gemm(const unsigned short* __restrict__ A,
    const unsigned short* __restrict__ Bt, float* __restrict__ P,
    int rows, int Ktot, int Kc){
  __shared__ unsigned short As[128*72];
  __shared__ unsigned short Bs[64*72];
  int t = threadIdx.x;
  int lane = t & 63;
  int w = t >> 6;
  int row0 = blockIdx.x*128;
  int k0 = blockIdx.y*Kc;

  int srow  = t >> 3;        // 0..31
  int skseg = (t & 7) << 3;  // elem 0,8,...,56

  float4v acc[2][4];
  #pragma unroll
  for(int rt=0;rt<2;rt++)
    #pragma unroll
    for(int ct=0;ct<4;ct++)
      #pragma unroll
      for(int q=0;q<4;q++) acc[rt][ct][q]=0.f;

  int lrow = lane & 15;
  int lk   = (lane >> 4) << 3;

  for(int kk=0; kk<Kc; kk+=GBK){
    __syncthreads();
    #pragma unroll
    for(int q=0;q<4;q++){
      int r = srow + 32*q;
      int gr = row0 + r;
      short8 val = {0,0,0,0,0,0,0,0};
      if(gr < rows) val = *(const short8*)(A + (size_t)gr*Ktot + k0 + kk + skseg);
      *(short8*)(As + r*72 + skseg) = val;
    }
    #pragma unroll
    for(int q=0;q<2;q++){
      int o = srow + 32*q;
      *(short8*)(Bs + o*72 + skseg) = *(const short8*)(Bt + (size_t)o*Ktot + k0 + kk + skseg);
    }
    __syncthreads();
    #pragma unroll
    for(int k32=0;k32<2;k32++){
      int kf = k32*32 + lk;
      short8 a0 = *(short8*)(As + (w*32      + lrow)*72 + kf);
      short8 a1 = *(short8*)(As + (w*32 + 16 + lrow)*72 + kf);
      #pragma unroll
      for(int ct=0;ct<4;ct++){
        short8 b = *(short8*)(Bs + (ct*16 + lrow)*72 + kf);
        acc[0][ct] = __builtin_amdgcn_mfma_f32_16x16x32_bf16(a0, b, acc[0][ct], 0,0,0);
        acc[1][ct] = __builtin_amdgcn_mfma_f32_16x16x32_bf16(a1, b, acc[1][ct], 0,0,0);
      }
    }
  }
  size_t base = (size_t)blockIdx.y*rows*64;
  int quad = lane >> 4;
  #pragma unroll
  for(int rt=0;rt<2;rt++){
    #pragma unroll
    for(int ct=0;ct<4;ct++){
      int c = ct*16 + lrow;
      #pragma unroll
      for(int reg=0;reg<4;reg++){
        int r = row0 + w*32 + rt*16 + quad*4 + reg;
        if(r < rows) P[base + (size_t)r*64 + c] = acc[rt][ct][reg];
      }
    }
  }
}

// ---------------- split reduction + epilogue (templated, float4, unrolled) ----------------
// one thread per (node, 4-output group): rows*16 threads.

template<int CIN, int SPLIT>
__global__ __launch_bounds__(256) void k_reduce_ep(const float* __restrict__ P, int rows, int v0,
    const float* __restrict__ XS, const float* __restrict__ b2, const float* __restrict__ xprev,
    const float* __restrict__ root, const float* __restrict__ bias, const int* __restrict__ offs,
    float* __restrict__ out){
  int idx = blockIdx.x*256 + threadIdx.x;
  if(idx >= rows*16) return;
  int r = idx >> 4, og = (idx & 15) << 2;
  int v = v0 + r;

  float4 s = make_float4(0.f,0.f,0.f,0.f);
  #pragma unroll
  for(int z=0; z<SPLIT; z++){
    float4 p = *(const float4*)(P + ((size_t)z*rows + r)*64 + og);
    s.x += p.x; s.y += p.y; s.z += p.z; s.w += p.w;
  }
  // xb: Σ_i XS[v,i] * b2[i*64+og..] -- added before mean division
  #pragma unroll
  for(int i=0;i<CIN;i++){
    float xsv = XS[(size_t)v*64 + i];
    float4 b = *(const float4*)(b2 + i*64 + og);
    s.x += xsv*b.x; s.y += xsv*b.y; s.z += xsv*b.z; s.w += xsv*b.w;
  }
  // root term: Σ_i xprev[v,i] * root[i*64+og..]
  float4 rt = make_float4(0.f,0.f,0.f,0.f);
  #pragma unroll
  for(int i=0;i<CIN;i++){
    float xv = xprev[(size_t)v*CIN + i];
    float4 wv = *(const float4*)(root + i*64 + og);
    rt.x += xv*wv.x; rt.y += xv*wv.y; rt.z += xv*wv.z; rt.w += xv*wv.w;
  }
  float c = (float)(offs[v+1]-offs[v]); c = fmaxf(c, 1.f);
  float inv = 1.f/c;
  float4 bi = *(const float4*)(bias + og);
  float4 o;
  o.x = fmaxf(s.x*inv + rt.x + bi.x, 0.f);
  o.y = fmaxf(s.y*inv + rt.y + bi.y, 0.f);
  o.z = fmaxf(s.z*inv + rt.z + bi.z, 0.f);
  o.w = fmaxf(s.w*inv + rt.w + bi.w, 0.f);
  *(float4*)(out + (size_t)v*64 + og) = o;
}

// ---------------- readout MLP ----------------

__global__ void k_readout(const float* __restrict__ x2, const float* __restrict__ lw1,
                          const float* __restrict__ lb1, const float* __restrict__ lw2,
                          const float* __restrict__ lb2, float* __restrict__ out){
  int v = blockIdx.x*256 + threadIdx.x;
  if(v >= NN) return;
  float accj[8];
  #pragma unroll
  for(int j=0;j<8;j++) accj[j] = lb1[j];
  const float* xr = x2 + (size_t)v*64;
  #pragma unroll 16
  for(int i=0;i<64;i++){
    float xv = xr[i];
    #pragma unroll
    for(int j=0;j<8;j++) accj[j] += xv*lw1[i*8+j];
  }
  float o = lb2[0];
  #pragma unroll
  for(int j=0;j<8;j++) o += fmaxf(accj[j],0.f)*lw2[j];
  out[v] = o;
}

// ---------------- host ----------------

extern "C" void kernel_launch(void* const* d_in, const int* in_sizes, int n_in,
                              void* d_out, int out_size, void* d_ws, size_t ws_size,
                              hipStream_t stream) {
  const float* x      = (const float*)d_in[0];
  const int*   ei     = (const int*)d_in[1];
  const float* ea     = (const float*)d_in[2];
  const float* nn1_w1 = (const float*)d_in[3];
  const float* nn1_b1 = (const float*)d_in[4];
  const float* nn1_w2 = (const float*)d_in[5];
  const float* nn1_b2 = (const float*)d_in[6];
  const float* root1  = (const float*)d_in[7];
  const float* bias1  = (const float*)d_in[8];
  const float* nn2_w1 = (const float*)d_in[9];
  const float* nn2_b1 = (const float*)d_in[10];
  const float* nn2_w2 = (const float*)d_in[11];
  const float* nn2_b2 = (const float*)d_in[12];
  const float* root2  = (const float*)d_in[13];
  const float* bias2  = (const float*)d_in[14];
  const float* lin1_w = (const float*)d_in[15];
  const float* lin1_b = (const float*)d_in[16];
  const float* lin2_w = (const float*)d_in[17];
  const float* lin2_b = (const float*)d_in[18];
  float* out = (float*)d_out;

  const int* srcIdx = ei;
  const int* dstIdx = ei + EE;

  char* w = (char*)d_ws;
  size_t off = 0;
  auto alloc = [&](size_t bytes)->void*{
    void* p = w + off;
    off = (off + bytes + 255) & ~(size_t)255;
    return p;
  };
  int*            cnt    = (int*)           alloc((size_t)NN*4);
  int*            offs   = (int*)           alloc((size_t)(NN+1)*4);
  int*            cursor = (int*)           alloc((size_t)NN*4);
  int*            elist  = (int*)           alloc((size_t)EE*4);
  float*          h      = (float*)         alloc((size_t)EE*64*4);
  float*          XS     = (float*)         alloc((size_t)NN*64*4);
  float*          x1     = (float*)         alloc((size_t)NN*64*4);
  float*          x2b    = (float*)         alloc((size_t)NN*64*4);
  unsigned short* Bp     = (unsigned short*)alloc((size_t)4096*64*2);
  size_t fixedBytes = off;
  size_t R = (ws_size > fixedBytes) ? (ws_size - fixedBytes) : 0;

  const int S1 = 8, S2 = 16;
  long long C2max = (long long)(R / (4096*2 + S2*64*4));
  long long C1max = (long long)(R / (1024*2 + S1*64*4));
  if(C2max > NN) C2max = NN;
  if(C1max > NN) C1max = NN;
  if(C2max < 128) C2max = 128;
  if(C1max < 128) C1max = 128;
  int nch2 = (int)((NN + C2max - 1)/C2max);
  int nch1 = (int)((NN + C1max - 1)/C1max);
  long long C2 = (NN + nch2 - 1)/nch2;
  long long C1 = (NN + nch1 - 1)/nch1;

  unsigned short* Kbuf = (unsigned short*)(w + off);

  // CSR by dst
  hipMemsetAsync(cnt, 0, (size_t)NN*4, stream);
  k_hist   <<<(EE+255)/256, 256, 0, stream>>>(dstIdx, cnt);
  k_scan   <<<1, 1024, 0, stream>>>(cnt, offs, cursor);
  k_scatter<<<(EE+255)/256, 256, 0, stream>>>(dstIdx, cursor, elist);

  // ---------- layer 1 (cin=16, Ktot=1024) ----------
  k_permB   <<<(64*16*64+255)/256, 256, 0, stream>>>(nn1_w2, Bp, 16);
  k_edge_mlp<<<(EE*64+255)/256, 256, 0, stream>>>(ea, nn1_w1, nn1_b1, h);
  {
    float* P = (float*)(w + off + (size_t)C1*1024*2);
    for(long long v0=0; v0<NN; v0+=C1){
      int rows = (int)((NN - v0 < C1) ? (NN - v0) : C1);
      k_accK1<<<rows, 64, 0, stream>>>(x, srcIdx, offs, elist, h, Kbuf, XS, (int)v0);
      dim3 g((rows+127)/128, S1);
      k_gemm<<<g, 256, 0, stream>>>(Kbuf, Bp, P, rows, 1024, 1024/S1);
      k_reduce_ep<16,S1><<<(rows*16+255)/256, 256, 0, stream>>>(P, rows, (int)v0, XS, nn1_b2, x,
                                                                 root1, bias1, offs, x1);
    }
  }

  // ---------- layer 2 (cin=64, Ktot=4096) ----------
  k_permB   <<<(64*64*64+255)/256, 256, 0, stream>>>(nn2_w2, Bp, 64);
  k_edge_mlp<<<(EE*64+255)/256, 256, 0, stream>>>(ea, nn2_w1, nn2_b1, h);
  {
    float* P = (float*)(w + off + (size_t)C2*4096*2);
    for(long long v0=0; v0<NN; v0+=C2){
      int rows = (int)((NN - v0 < C2) ? (NN - v0) : C2);
      k_accK2<<<rows, 64, 0, stream>>>(x1, srcIdx, offs, elist, h, Kbuf, XS, (int)v0);
      dim3 g((rows+127)/128, S2);
      k_gemm<<<g, 256, 0, stream>>>(Kbuf, Bp, P, rows, 4096, 4096/S2);
      k_reduce_ep<64,S2><<<(rows*16+255)/256, 256, 0, stream>>>(P, rows, (int)v0, XS, nn2_b2, x1,
                                                                 root2, bias2, offs, x2b);
    }
  }

  // ---------- readout ----------
  k_readout<<<(NN+255)/256, 256, 0, stream>>>(x2b, lin1_w, lin1_b, lin2_w, lin2_b, out);
}

// Round 5
// 226.325 us; speedup vs baseline: 1.8329x; 1.0609x over previous
//
#include <hip/hip_runtime.h>
#include <hip/hip_bf16.h>

#define NN 10000
#define EE 65536

using short8  = __attribute__((ext_vector_type(8))) short;
using float4v = __attribute__((ext_vector_type(4))) float;

__device__ __forceinline__ unsigned short f2b(float f){
  union { float f; unsigned int u; } v; v.f = f;
  unsigned int u = v.u;
  unsigned int r = (u + 0x7fff + ((u >> 16) & 1)) >> 16;  // RNE
  return (unsigned short)r;
}

// ---------------- fused prep: zero cnt, permB x2, edge_mlp x2 ----------------
// block ranges: [0,40) zero cnt | [40,296) permB1 | [296,1320) permB2
//               [1320,17704) mlp1 | [17704,34088) mlp2

__device__ __forceinline__ void do_permB(int idx, const float* __restrict__ w2,
                                         unsigned short* __restrict__ Bt, int cin){
  int K = cin*64;
  int o = idx / K;
  int k = idx - o*K;
  int m = k / cin;
  int i = k - m*cin;
  Bt[idx] = f2b(w2[(size_t)m*(cin*64) + i*64 + o]);
}

__device__ __forceinline__ void do_mlp(int idx, const float* __restrict__ ea,
                                       const float* __restrict__ w1, const float* __restrict__ b1,
                                       float* __restrict__ h){
  int m = idx & 63;
  int e = idx >> 6;
  const float* a = ea + (size_t)e*4;
  float acc = b1[m] + a[0]*w1[m] + a[1]*w1[64+m] + a[2]*w1[128+m] + a[3]*w1[192+m];
  h[idx] = fmaxf(acc, 0.f);
}

__global__ __launch_bounds__(256) void k_prep(const float* __restrict__ ea,
    const float* __restrict__ w1a, const float* __restrict__ b1a, float* __restrict__ h1,
    const float* __restrict__ w1b, const float* __restrict__ b1b, float* __restrict__ h2,
    const float* __restrict__ w2a, unsigned short* __restrict__ Bt1,
    const float* __restrict__ w2b, unsigned short* __restrict__ Bt2,
    int* __restrict__ cnt){
  int b = blockIdx.x;
  int t = threadIdx.x;
  if(b < 40){
    int i = b*256 + t;
    if(i < NN) cnt[i] = 0;
  } else if(b < 296){
    do_permB((b-40)*256 + t, w2a, Bt1, 16);
  } else if(b < 1320){
    do_permB((b-296)*256 + t, w2b, Bt2, 64);
  } else if(b < 17704){
    do_mlp((b-1320)*256 + t, ea, w1a, b1a, h1);
  } else {
    do_mlp((b-17704)*256 + t, ea, w1b, b1b, h2);
  }
}

// ---------------- CSR build ----------------

__global__ void k_hist(const int* __restrict__ dst, int* __restrict__ cnt){
  int e = blockIdx.x*256 + threadIdx.x;
  if(e < EE) atomicAdd(&cnt[dst[e]], 1);
}

__global__ __launch_bounds__(1024) void k_scan(const int* __restrict__ cnt, int* __restrict__ offs, int* __restrict__ cursor){
  const int T = 1024, PER = (NN + T - 1)/T; // 10
  int tid = threadIdx.x;
  int base = tid*PER;
  int local[PER];
  int s = 0;
  #pragma unroll
  for(int j=0;j<PER;j++){
    int i = base+j;
    int v = (i<NN)? cnt[i] : 0;
    local[j] = s;
    s += v;
  }
  int lane = tid & 63, wv = tid >> 6;
  int val = s;
  #pragma unroll
  for(int o=1;o<64;o<<=1){
    int u = __shfl_up(val, o, 64);
    if(lane >= o) val += u;
  }
  __shared__ int wsum[16];
  if(lane==63) wsum[wv] = val;
  __syncthreads();
  if(tid==0){
    int acc=0;
    #pragma unroll
    for(int i=0;i<16;i++){ int t2=wsum[i]; wsum[i]=acc; acc+=t2; }
  }
  __syncthreads();
  int thr_excl = wsum[wv] + (val - s);
  #pragma unroll
  for(int j=0;j<PER;j++){
    int i = base+j;
    if(i<NN){ int e = thr_excl + local[j]; offs[i]=e; cursor[i]=e; }
  }
  if(tid == T-1) offs[NN] = thr_excl + s;
}

__global__ void k_scatter(const int* __restrict__ dst, int* __restrict__ cursor, int* __restrict__ elist){
  int e = blockIdx.x*256 + threadIdx.x;
  if(e < EE){ int p = atomicAdd(&cursor[dst[e]], 1); elist[p] = e; }
}

// ---------------- per-dst rank-1 accumulation, cin=16 (one wave per node) ----------------
// lane L: i = L&15, mg = L>>4; acc over m = mg*16+j.  K1 layout: k = m*16 + i (bf16).

__global__ __launch_bounds__(64) void k_accK1(const float* __restrict__ x, const int* __restrict__ src,
    const int* __restrict__ offs, const int* __restrict__ elist, const float* __restrict__ h,
    unsigned short* __restrict__ K1, float* __restrict__ XS, int v0){
  int v = v0 + blockIdx.x;
  int L = threadIdx.x;
  int i = L & 15, mg = L >> 4;
  __shared__ float sh[2][64];
  float acc[16];
  #pragma unroll
  for(int j=0;j<16;j++) acc[j]=0.f;
  float xs = 0.f;
  int p0 = offs[v], p1 = offs[v+1];
  float h_nxt = 0.f, x_nxt = 0.f;
  if(p0 < p1){
    int e = elist[p0];
    h_nxt = h[(size_t)e*64 + L];
    x_nxt = x[(size_t)src[e]*16 + i];
  }
  for(int p=p0;p<p1;p++){
    int buf = (p-p0)&1;
    float hv = h_nxt, xv = x_nxt;
    sh[buf][L] = hv;
    __syncthreads();
    if(p+1<p1){
      int e = elist[p+1];
      h_nxt = h[(size_t)e*64 + L];
      x_nxt = x[(size_t)src[e]*16 + i];
    }
    xs += xv;
    #pragma unroll
    for(int j4=0;j4<4;j4++){
      float4 h4 = *(float4*)&sh[buf][mg*16 + j4*4];
      acc[j4*4+0] += h4.x*xv; acc[j4*4+1] += h4.y*xv;
      acc[j4*4+2] += h4.z*xv; acc[j4*4+3] += h4.w*xv;
    }
  }
  unsigned short* Kv = K1 + (size_t)blockIdx.x*1024;
  #pragma unroll
  for(int j=0;j<16;j++) Kv[(mg*16+j)*16 + i] = f2b(acc[j]);
  if(mg==0) XS[(size_t)v*64 + i] = xs;
}

// ---------------- per-dst rank-1 accumulation, cin=64 (one wave per node) ----------------
// lane L: q=L&15, mg=L>>4; columns i0=q*4..+3, m = mg*16+j. 4 ds_read_b128/edge.
// K layout: k = m*64 + i (bf16).

__global__ __launch_bounds__(64) void k_accK2(const float* __restrict__ x1, const int* __restrict__ src,
    const int* __restrict__ offs, const int* __restrict__ elist, const float* __restrict__ h,
    unsigned short* __restrict__ K, float* __restrict__ XS, int v0){
  int v = v0 + blockIdx.x;
  int L = threadIdx.x;
  int q = L & 15, mg = L >> 4;
  int i0 = q << 2;
  __shared__ float sh[2][64];
  float acc[16][4];
  #pragma unroll
  for(int j=0;j<16;j++)
    #pragma unroll
    for(int c=0;c<4;c++) acc[j][c]=0.f;
  float4 xs = make_float4(0.f,0.f,0.f,0.f);
  int p0 = offs[v], p1 = offs[v+1];
  float h_nxt = 0.f;
  float4 x_nxt = make_float4(0.f,0.f,0.f,0.f);
  if(p0 < p1){
    int e = elist[p0];
    h_nxt = h[(size_t)e*64 + L];
    x_nxt = *(const float4*)(x1 + (size_t)src[e]*64 + i0);
  }
  for(int p=p0;p<p1;p++){
    int buf = (p-p0)&1;
    float4 xv = x_nxt;
    sh[buf][L] = h_nxt;
    __syncthreads();
    if(p+1<p1){
      int e = elist[p+1];
      h_nxt = h[(size_t)e*64 + L];
      x_nxt = *(const float4*)(x1 + (size_t)src[e]*64 + i0);
    }
    xs.x += xv.x; xs.y += xv.y; xs.z += xv.z; xs.w += xv.w;
    #pragma unroll
    for(int j4=0;j4<4;j4++){
      float4 h4 = *(float4*)&sh[buf][mg*16 + j4*4];
      #pragma unroll
      for(int tq=0;tq<4;tq++){
        float hv = (tq==0)?h4.x:(tq==1)?h4.y:(tq==2)?h4.z:h4.w;
        acc[j4*4+tq][0] += hv*xv.x; acc[j4*4+tq][1] += hv*xv.y;
        acc[j4*4+tq][2] += hv*xv.z; acc[j4*4+tq][3] += hv*xv.w;
      }
    }
  }
  unsigned short* Kv = K + (size_t)blockIdx.x*4096;
  #pragma unroll
  for(int j=0;j<16;j++){
    ushort4 u;
    u.x = f2b(acc[j][0]); u.y = f2b(acc[j][1]); u.z = f2b(acc[j][2]); u.w = f2b(acc[j][3]);
    *(ushort4*)(Kv + (mg*16+j)*64 + i0) = u;
  }
  if(mg==0) *(float4*)(XS + (size_t)v*64 + i0) = xs;
}

// ---------------- MFMA split-K GEMM ----------------

#define GBK 64

__global__ __launch_bounds__(256) void k_gemm(const unsigned short* __restrict__ A,
    const unsigned short* __restrict__ Bt, float* __restrict__ P,
    int rows, int Ktot, int Kc){
  __shared__ unsigned short As[128*72];
  __shared__ unsigned short Bs[64*72];
  int t = threadIdx.x;
  int lane = t & 63;
  int w = t >> 6;
  int row0 = blockIdx.x*128;
  int k0 = blockIdx.y*Kc;

  int srow  = t >> 3;        // 0..31
  int skseg = (t & 7) << 3;  // elem 0,8,...,56

  float4v acc[2][4];
  #pragma unroll
  for(int rt=0;rt<2;rt++)
    #pragma unroll
    for(int ct=0;ct<4;ct++)
      #pragma unroll
      for(int qq=0;qq<4;qq++) acc[rt][ct][qq]=0.f;

  int lrow = lane & 15;
  int lk   = (lane >> 4) << 3;

  for(int kk=0; kk<Kc; kk+=GBK){
    __syncthreads();
    #pragma unroll
    for(int qq=0;qq<4;qq++){
      int r = srow + 32*qq;
      int gr = row0 + r;
      short8 val = {0,0,0,0,0,0,0,0};
      if(gr < rows) val = *(const short8*)(A + (size_t)gr*Ktot + k0 + kk + skseg);
      *(short8*)(As + r*72 + skseg) = val;
    }
    #pragma unroll
    for(int qq=0;qq<2;qq++){
      int o = srow + 32*qq;
      *(short8*)(Bs + o*72 + skseg) = *(const short8*)(Bt + (size_t)o*Ktot + k0 + kk + skseg);
    }
    __syncthreads();
    #pragma unroll
    for(int k32=0;k32<2;k32++){
      int kf = k32*32 + lk;
      short8 a0 = *(short8*)(As + (w*32      + lrow)*72 + kf);
      short8 a1 = *(short8*)(As + (w*32 + 16 + lrow)*72 + kf);
      #pragma unroll
      for(int ct=0;ct<4;ct++){
        short8 b = *(short8*)(Bs + (ct*16 + lrow)*72 + kf);
        acc[0][ct] = __builtin_amdgcn_mfma_f32_16x16x32_bf16(a0, b, acc[0][ct], 0,0,0);
        acc[1][ct] = __builtin_amdgcn_mfma_f32_16x16x32_bf16(a1, b, acc[1][ct], 0,0,0);
      }
    }
  }
  size_t base = (size_t)blockIdx.y*rows*64;
  int quad = lane >> 4;
  #pragma unroll
  for(int rt=0;rt<2;rt++){
    #pragma unroll
    for(int ct=0;ct<4;ct++){
      int c = ct*16 + lrow;
      #pragma unroll
      for(int reg=0;reg<4;reg++){
        int r = row0 + w*32 + rt*16 + quad*4 + reg;
        if(r < rows) P[base + (size_t)r*64 + c] = acc[rt][ct][reg];
      }
    }
  }
}

// ---------------- split reduction + epilogue (layer1 / fallback) ----------------

template<int CIN, int SPLIT>
__global__ __launch_bounds__(256) void k_reduce_ep(const float* __restrict__ P, int rows, int v0,
    const float* __restrict__ XS, const float* __restrict__ b2, const float* __restrict__ xprev,
    const float* __restrict__ root, const float* __restrict__ bias, const int* __restrict__ offs,
    float* __restrict__ out){
  int idx = blockIdx.x*256 + threadIdx.x;
  if(idx >= rows*16) return;
  int r = idx >> 4, og = (idx & 15) << 2;
  int v = v0 + r;

  float4 s = make_float4(0.f,0.f,0.f,0.f);
  #pragma unroll
  for(int z=0; z<SPLIT; z++){
    float4 p = *(const float4*)(P + ((size_t)z*rows + r)*64 + og);
    s.x += p.x; s.y += p.y; s.z += p.z; s.w += p.w;
  }
  #pragma unroll
  for(int i=0;i<CIN;i++){
    float xsv = XS[(size_t)v*64 + i];
    float4 b = *(const float4*)(b2 + i*64 + og);
    s.x += xsv*b.x; s.y += xsv*b.y; s.z += xsv*b.z; s.w += xsv*b.w;
  }
  float4 rt = make_float4(0.f,0.f,0.f,0.f);
  #pragma unroll
  for(int i=0;i<CIN;i++){
    float xv = xprev[(size_t)v*CIN + i];
    float4 wv = *(const float4*)(root + i*64 + og);
    rt.x += xv*wv.x; rt.y += xv*wv.y; rt.z += xv*wv.z; rt.w += xv*wv.w;
  }
  float c = (float)(offs[v+1]-offs[v]); c = fmaxf(c, 1.f);
  float inv = 1.f/c;
  float4 bi = *(const float4*)(bias + og);
  float4 o;
  o.x = fmaxf(s.x*inv + rt.x + bi.x, 0.f);
  o.y = fmaxf(s.y*inv + rt.y + bi.y, 0.f);
  o.z = fmaxf(s.z*inv + rt.z + bi.z, 0.f);
  o.w = fmaxf(s.w*inv + rt.w + bi.w, 0.f);
  *(float4*)(out + (size_t)v*64 + og) = o;
}

// ---------------- layer-2 reduction + epilogue + fused readout ----------------
// 256 threads = 16 nodes x 16 threads. Single-chunk only (v0 = 0).

template<int SPLIT>
__global__ __launch_bounds__(256) void k_red2_ro(const float* __restrict__ P, int rows,
    const float* __restrict__ XS, const float* __restrict__ b2, const float* __restrict__ x1,
    const float* __restrict__ root, const float* __restrict__ bias, const int* __restrict__ offs,
    const float* __restrict__ lw1, const float* __restrict__ lb1,
    const float* __restrict__ lw2, const float* __restrict__ lb2,
    float* __restrict__ out){
  __shared__ float row[16][68];
  __shared__ float hjs[16][8];
  int tid = threadIdx.x;
  int idx = blockIdx.x*256 + tid;
  int r = idx >> 4, og = (idx & 15) << 2;
  int n = tid >> 4;
  int nbase = blockIdx.x*16;
  int ninblk = rows - nbase; if(ninblk > 16) ninblk = 16;

  float4 o = make_float4(0.f,0.f,0.f,0.f);
  if(r < rows){
    float4 s = make_float4(0.f,0.f,0.f,0.f);
    #pragma unroll
    for(int z=0; z<SPLIT; z++){
      float4 p = *(const float4*)(P + ((size_t)z*rows + r)*64 + og);
      s.x += p.x; s.y += p.y; s.z += p.z; s.w += p.w;
    }
    #pragma unroll
    for(int i=0;i<64;i++){
      float xsv = XS[(size_t)r*64 + i];
      float4 b = *(const float4*)(b2 + i*64 + og);
      s.x += xsv*b.x; s.y += xsv*b.y; s.z += xsv*b.z; s.w += xsv*b.w;
    }
    float4 rt = make_float4(0.f,0.f,0.f,0.f);
    #pragma unroll
    for(int i=0;i<64;i++){
      float xv = x1[(size_t)r*64 + i];
      float4 wv = *(const float4*)(root + i*64 + og);
      rt.x += xv*wv.x; rt.y += xv*wv.y; rt.z += xv*wv.z; rt.w += xv*wv.w;
    }
    float c = (float)(offs[r+1]-offs[r]); c = fmaxf(c, 1.f);
    float inv = 1.f/c;
    float4 bi = *(const float4*)(bias + og);
    o.x = fmaxf(s.x*inv + rt.x + bi.x, 0.f);
    o.y = fmaxf(s.y*inv + rt.y + bi.y, 0.f);
    o.z = fmaxf(s.z*inv + rt.z + bi.z, 0.f);
    o.w = fmaxf(s.w*inv + rt.w + bi.w, 0.f);
  }
  *(float4*)&row[n][og] = o;
  __syncthreads();
  // stage 1: 8 hidden units per node, 128 threads active
  if(tid < 128){
    int n2 = tid >> 3, j = tid & 7;
    if(n2 < ninblk){
      float a = lb1[j];
      #pragma unroll
      for(int i=0;i<64;i++) a += row[n2][i]*lw1[i*8+j];
      hjs[n2][j] = fmaxf(a, 0.f)*lw2[j];
    }
  }
  __syncthreads();
  if(tid < 16 && tid < ninblk){
    float s = lb2[0];
    #pragma unroll
    for(int j=0;j<8;j++) s += hjs[tid][j];
    out[nbase + tid] = s;
  }
}

// ---------------- readout (fallback path only) ----------------

__global__ void k_readout(const float* __restrict__ x2, const float* __restrict__ lw1,
                          const float* __restrict__ lb1, const float* __restrict__ lw2,
                          const float* __restrict__ lb2, float* __restrict__ out){
  int v = blockIdx.x*256 + threadIdx.x;
  if(v >= NN) return;
  float accj[8];
  #pragma unroll
  for(int j=0;j<8;j++) accj[j] = lb1[j];
  const float* xr = x2 + (size_t)v*64;
  #pragma unroll 16
  for(int i=0;i<64;i++){
    float xv = xr[i];
    #pragma unroll
    for(int j=0;j<8;j++) accj[j] += xv*lw1[i*8+j];
  }
  float o = lb2[0];
  #pragma unroll
  for(int j=0;j<8;j++) o += fmaxf(accj[j],0.f)*lw2[j];
  out[v] = o;
}

// ---------------- host ----------------

extern "C" void kernel_launch(void* const* d_in, const int* in_sizes, int n_in,
                              void* d_out, int out_size, void* d_ws, size_t ws_size,
                              hipStream_t stream) {
  const float* x      = (const float*)d_in[0];
  const int*   ei     = (const int*)d_in[1];
  const float* ea     = (const float*)d_in[2];
  const float* nn1_w1 = (const float*)d_in[3];
  const float* nn1_b1 = (const float*)d_in[4];
  const float* nn1_w2 = (const float*)d_in[5];
  const float* nn1_b2 = (const float*)d_in[6];
  const float* root1  = (const float*)d_in[7];
  const float* bias1  = (const float*)d_in[8];
  const float* nn2_w1 = (const float*)d_in[9];
  const float* nn2_b1 = (const float*)d_in[10];
  const float* nn2_w2 = (const float*)d_in[11];
  const float* nn2_b2 = (const float*)d_in[12];
  const float* root2  = (const float*)d_in[13];
  const float* bias2  = (const float*)d_in[14];
  const float* lin1_w = (const float*)d_in[15];
  const float* lin1_b = (const float*)d_in[16];
  const float* lin2_w = (const float*)d_in[17];
  const float* lin2_b = (const float*)d_in[18];
  float* out = (float*)d_out;

  const int* srcIdx = ei;
  const int* dstIdx = ei + EE;

  char* w = (char*)d_ws;
  size_t off = 0;
  auto alloc = [&](size_t bytes)->void*{
    void* p = w + off;
    off = (off + bytes + 255) & ~(size_t)255;
    return p;
  };
  int*            cnt    = (int*)           alloc((size_t)NN*4);
  int*            offs   = (int*)           alloc((size_t)(NN+1)*4);
  int*            cursor = (int*)           alloc((size_t)NN*4);
  int*            elist  = (int*)           alloc((size_t)EE*4);
  float*          h1     = (float*)         alloc((size_t)EE*64*4);
  float*          h2     = (float*)         alloc((size_t)EE*64*4);
  float*          XS     = (float*)         alloc((size_t)NN*64*4);
  float*          x1     = (float*)         alloc((size_t)NN*64*4);
  unsigned short* Bt1    = (unsigned short*)alloc((size_t)64*1024*2);
  unsigned short* Bt2    = (unsigned short*)alloc((size_t)64*4096*2);
  size_t fixedBytes = off;
  size_t R = (ws_size > fixedBytes) ? (ws_size - fixedBytes) : 0;

  const int S1 = 4, S2 = 8;
  size_t needSingle = (size_t)NN*4096*2 + (size_t)S2*NN*64*4;  // K2 + P2 (dominant)
  bool single = (R >= needSingle + 4096);

  // prep (zero cnt, permB1/2, mlp1/2): 40 + 256 + 1024 + 16384 + 16384 blocks
  k_prep<<<34088, 256, 0, stream>>>(ea, nn1_w1, nn1_b1, h1, nn2_w1, nn2_b1, h2,
                                    nn1_w2, Bt1, nn2_w2, Bt2, cnt);
  k_hist   <<<(EE+255)/256, 256, 0, stream>>>(dstIdx, cnt);
  k_scan   <<<1, 1024, 0, stream>>>(cnt, offs, cursor);
  k_scatter<<<(EE+255)/256, 256, 0, stream>>>(dstIdx, cursor, elist);

  if(single){
    unsigned short* Kbuf = (unsigned short*)(w + off);
    float* P = (float*)(w + off + (size_t)NN*4096*2);

    // ---------- layer 1 ----------
    k_accK1<<<NN, 64, 0, stream>>>(x, srcIdx, offs, elist, h1, Kbuf, XS, 0);
    {
      dim3 g((NN+127)/128, S1);
      k_gemm<<<g, 256, 0, stream>>>(Kbuf, Bt1, P, NN, 1024, 1024/S1);
    }
    k_reduce_ep<16,S1><<<(NN*16+255)/256, 256, 0, stream>>>(P, NN, 0, XS, nn1_b2, x,
                                                             root1, bias1, offs, x1);
    // ---------- layer 2 + fused readout ----------
    k_accK2<<<NN, 64, 0, stream>>>(x1, srcIdx, offs, elist, h2, Kbuf, XS, 0);
    {
      dim3 g((NN+127)/128, S2);
      k_gemm<<<g, 256, 0, stream>>>(Kbuf, Bt2, P, NN, 4096, 4096/S2);
    }
    k_red2_ro<S2><<<(NN+15)/16, 256, 0, stream>>>(P, NN, XS, nn2_b2, x1, root2, bias2, offs,
                                                   lin1_w, lin1_b, lin2_w, lin2_b, out);
  } else {
    // fallback: chunked, separate readout
    float* x2b = (float*)alloc((size_t)NN*64*4);
    R = (ws_size > off) ? (ws_size - off) : 0;
    long long C2 = (long long)(R / (4096*2 + S2*64*4));
    long long C1 = (long long)(R / (1024*2 + S1*64*4));
    if(C2 > NN) C2 = NN; if(C1 > NN) C1 = NN;
    if(C2 < 128) C2 = 128; if(C1 < 128) C1 = 128;
    unsigned short* Kbuf = (unsigned short*)(w + off);
    {
      float* P = (float*)(w + off + (size_t)C1*1024*2);
      for(long long v0=0; v0<NN; v0+=C1){
        int rows = (int)((NN - v0 < C1) ? (NN - v0) : C1);
        k_accK1<<<rows, 64, 0, stream>>>(x, srcIdx, offs, elist, h1, Kbuf, XS, (int)v0);
        dim3 g((rows+127)/128, S1);
        k_gemm<<<g, 256, 0, stream>>>(Kbuf, Bt1, P, rows, 1024, 1024/S1);
        k_reduce_ep<16,S1><<<(rows*16+255)/256, 256, 0, stream>>>(P, rows, (int)v0, XS, nn1_b2, x,
                                                                   root1, bias1, offs, x1);
      }
    }
    {
      float* P = (float*)(w + off + (size_t)C2*4096*2);
      for(long long v0=0; v0<NN; v0+=C2){
        int rows = (int)((NN - v0 < C2) ? (NN - v0) : C2);
        k_accK2<<<rows, 64, 0, stream>>>(x1, srcIdx, offs, elist, h2, Kbuf, XS, (int)v0);
        dim3 g((rows+127)/128, S2);
        k_gemm<<<g, 256, 0, stream>>>(Kbuf, Bt2, P, rows, 4096, 4096/S2);
        k_reduce_ep<64,S2><<<(rows*16+255)/256, 256, 0, stream>>>(P, rows, (int)v0, XS, nn2_b2, x1,
                                                                   root2, bias2, offs, x2b);
      }
    }
    k_readout<<<(NN+255)/256, 256, 0, stream>>>(x2b, lin1_w, lin1_b, lin2_w, lin2_b, out);
  }
}

// Round 6
// 219.801 us; speedup vs baseline: 1.8873x; 1.0297x over previous
//
#include <hip/hip_runtime.h>
#include <hip/hip_bf16.h>

#define NN 10000
#define EE 65536

using short8  = __attribute__((ext_vector_type(8))) short;
using u16x8   = __attribute__((ext_vector_type(8))) unsigned short;
using float4v = __attribute__((ext_vector_type(4))) float;

__device__ __forceinline__ unsigned short f2b(float f){
  union { float f; unsigned int u; } v; v.f = f;
  unsigned int u = v.u;
  unsigned int r = (u + 0x7fff + ((u >> 16) & 1)) >> 16;  // RNE
  return (unsigned short)r;
}

// ---------------- fused prep: zero cnt, permB x2, edge_mlp x2 ----------------

__device__ __forceinline__ void do_permB(int idx, const float* __restrict__ w2,
                                         unsigned short* __restrict__ Bt, int cin){
  int K = cin*64;
  int o = idx / K;
  int k = idx - o*K;
  int m = k / cin;
  int i = k - m*cin;
  Bt[idx] = f2b(w2[(size_t)m*(cin*64) + i*64 + o]);
}

__device__ __forceinline__ void do_mlp(int idx, const float* __restrict__ ea,
                                       const float* __restrict__ w1, const float* __restrict__ b1,
                                       float* __restrict__ h){
  int m = idx & 63;
  int e = idx >> 6;
  const float* a = ea + (size_t)e*4;
  float acc = b1[m] + a[0]*w1[m] + a[1]*w1[64+m] + a[2]*w1[128+m] + a[3]*w1[192+m];
  h[idx] = fmaxf(acc, 0.f);
}

__global__ __launch_bounds__(256) void k_prep(const float* __restrict__ ea,
    const float* __restrict__ w1a, const float* __restrict__ b1a, float* __restrict__ h1,
    const float* __restrict__ w1b, const float* __restrict__ b1b, float* __restrict__ h2,
    const float* __restrict__ w2a, unsigned short* __restrict__ Bt1,
    const float* __restrict__ w2b, unsigned short* __restrict__ Bt2,
    int* __restrict__ cnt){
  int b = blockIdx.x;
  int t = threadIdx.x;
  if(b < 40){
    int i = b*256 + t;
    if(i < NN) cnt[i] = 0;
  } else if(b < 296){
    do_permB((b-40)*256 + t, w2a, Bt1, 16);
  } else if(b < 1320){
    do_permB((b-296)*256 + t, w2b, Bt2, 64);
  } else if(b < 17704){
    do_mlp((b-1320)*256 + t, ea, w1a, b1a, h1);
  } else {
    do_mlp((b-17704)*256 + t, ea, w1b, b1b, h2);
  }
}

// ---------------- CSR build ----------------

__global__ void k_hist(const int* __restrict__ dst, int* __restrict__ cnt){
  int e = blockIdx.x*256 + threadIdx.x;
  if(e < EE) atomicAdd(&cnt[dst[e]], 1);
}

__global__ __launch_bounds__(1024) void k_scan(const int* __restrict__ cnt, int* __restrict__ offs, int* __restrict__ cursor){
  const int T = 1024, PER = (NN + T - 1)/T; // 10
  int tid = threadIdx.x;
  int base = tid*PER;
  int local[PER];
  int s = 0;
  #pragma unroll
  for(int j=0;j<PER;j++){
    int i = base+j;
    int v = (i<NN)? cnt[i] : 0;
    local[j] = s;
    s += v;
  }
  int lane = tid & 63, wv = tid >> 6;
  int val = s;
  #pragma unroll
  for(int o=1;o<64;o<<=1){
    int u = __shfl_up(val, o, 64);
    if(lane >= o) val += u;
  }
  __shared__ int wsum[16];
  if(lane==63) wsum[wv] = val;
  __syncthreads();
  if(tid==0){
    int acc=0;
    #pragma unroll
    for(int i=0;i<16;i++){ int t2=wsum[i]; wsum[i]=acc; acc+=t2; }
  }
  __syncthreads();
  int thr_excl = wsum[wv] + (val - s);
  #pragma unroll
  for(int j=0;j<PER;j++){
    int i = base+j;
    if(i<NN){ int e = thr_excl + local[j]; offs[i]=e; cursor[i]=e; }
  }
  if(tid == T-1) offs[NN] = thr_excl + s;
}

__global__ void k_scatter(const int* __restrict__ dst, int* __restrict__ cursor, int* __restrict__ elist){
  int e = blockIdx.x*256 + threadIdx.x;
  if(e < EE){ int p = atomicAdd(&cursor[dst[e]], 1); elist[p] = e; }
}

// ---------------- per-dst rank-1 accumulation, cin=16 (one wave per node) ----------------
// lane L: cg=L&3 (cols i0=cg*4..+3), mg=L>>2 (0..15), m = mg + 16j, j=0..3.
// K1 layout: k = m*16 + i (bf16). Stores: 4x ushort4 per lane.

__global__ __launch_bounds__(64) void k_accK1(const float* __restrict__ x, const int* __restrict__ src,
    const int* __restrict__ offs, const int* __restrict__ elist, const float* __restrict__ h,
    unsigned short* __restrict__ K1, float* __restrict__ XS, int v0){
  int v = v0 + blockIdx.x;
  int L = threadIdx.x;
  int cg = L & 3, mg = L >> 2;
  int i0 = cg << 2;
  __shared__ float sh[2][64];
  float acc[4][4];
  #pragma unroll
  for(int j=0;j<4;j++)
    #pragma unroll
    for(int c=0;c<4;c++) acc[j][c]=0.f;
  float4 xs = make_float4(0.f,0.f,0.f,0.f);
  int p0 = offs[v], p1 = offs[v+1];
  float h_nxt = 0.f;
  float4 x_nxt = make_float4(0.f,0.f,0.f,0.f);
  if(p0 < p1){
    int e = elist[p0];
    h_nxt = h[(size_t)e*64 + L];
    x_nxt = *(const float4*)(x + (size_t)src[e]*16 + i0);
  }
  for(int p=p0;p<p1;p++){
    int buf = (p-p0)&1;
    float4 xv = x_nxt;
    sh[buf][L] = h_nxt;
    __syncthreads();
    if(p+1<p1){
      int e = elist[p+1];
      h_nxt = h[(size_t)e*64 + L];
      x_nxt = *(const float4*)(x + (size_t)src[e]*16 + i0);
    }
    xs.x += xv.x; xs.y += xv.y; xs.z += xv.z; xs.w += xv.w;
    #pragma unroll
    for(int j=0;j<4;j++){
      float hv = sh[buf][mg + 16*j];
      acc[j][0] += hv*xv.x; acc[j][1] += hv*xv.y;
      acc[j][2] += hv*xv.z; acc[j][3] += hv*xv.w;
    }
  }
  unsigned short* Kv = K1 + (size_t)blockIdx.x*1024;
  #pragma unroll
  for(int j=0;j<4;j++){
    int m = mg + 16*j;
    ushort4 u;
    u.x=f2b(acc[j][0]); u.y=f2b(acc[j][1]); u.z=f2b(acc[j][2]); u.w=f2b(acc[j][3]);
    *(ushort4*)(Kv + m*16 + i0) = u;
  }
  if(mg==0) *(float4*)(XS + (size_t)v*64 + i0) = xs;
}

// ---------------- per-dst rank-1 accumulation, cin=64 (one wave per node) ----------------
// lane L: cg=L&7 (cols i0=cg*8..+7), mg=L>>3 (0..7), m = mg*8+j, j=0..7.
// K layout: k = m*64 + i (bf16). Stores: 8x u16x8 (16B) per lane.

__global__ __launch_bounds__(64) void k_accK2(const float* __restrict__ x1, const int* __restrict__ src,
    const int* __restrict__ offs, const int* __restrict__ elist, const float* __restrict__ h,
    unsigned short* __restrict__ K, float* __restrict__ XS, int v0){
  int v = v0 + blockIdx.x;
  int L = threadIdx.x;
  int cg = L & 7, mg = L >> 3;
  int i0 = cg << 3;
  __shared__ float sh[2][64];
  float acc[8][8];
  #pragma unroll
  for(int j=0;j<8;j++)
    #pragma unroll
    for(int c=0;c<8;c++) acc[j][c]=0.f;
  float4 xs0 = make_float4(0.f,0.f,0.f,0.f);
  float4 xs1 = make_float4(0.f,0.f,0.f,0.f);
  int p0 = offs[v], p1 = offs[v+1];
  float h_nxt = 0.f;
  float4 x_nxt0 = make_float4(0.f,0.f,0.f,0.f);
  float4 x_nxt1 = make_float4(0.f,0.f,0.f,0.f);
  if(p0 < p1){
    int e = elist[p0];
    h_nxt = h[(size_t)e*64 + L];
    const float* xr = x1 + (size_t)src[e]*64 + i0;
    x_nxt0 = *(const float4*)xr;
    x_nxt1 = *(const float4*)(xr+4);
  }
  for(int p=p0;p<p1;p++){
    int buf = (p-p0)&1;
    float4 xv0 = x_nxt0, xv1 = x_nxt1;
    sh[buf][L] = h_nxt;
    __syncthreads();
    if(p+1<p1){
      int e = elist[p+1];
      h_nxt = h[(size_t)e*64 + L];
      const float* xr = x1 + (size_t)src[e]*64 + i0;
      x_nxt0 = *(const float4*)xr;
      x_nxt1 = *(const float4*)(xr+4);
    }
    xs0.x += xv0.x; xs0.y += xv0.y; xs0.z += xv0.z; xs0.w += xv0.w;
    xs1.x += xv1.x; xs1.y += xv1.y; xs1.z += xv1.z; xs1.w += xv1.w;
    float4 h4a = *(float4*)&sh[buf][mg*8];
    float4 h4b = *(float4*)&sh[buf][mg*8+4];
    #pragma unroll
    for(int jj=0;jj<2;jj++){
      float4 h4 = jj? h4b : h4a;
      #pragma unroll
      for(int tq=0;tq<4;tq++){
        int j = jj*4+tq;
        float hv = (tq==0)?h4.x:(tq==1)?h4.y:(tq==2)?h4.z:h4.w;
        acc[j][0] += hv*xv0.x; acc[j][1] += hv*xv0.y;
        acc[j][2] += hv*xv0.z; acc[j][3] += hv*xv0.w;
        acc[j][4] += hv*xv1.x; acc[j][5] += hv*xv1.y;
        acc[j][6] += hv*xv1.z; acc[j][7] += hv*xv1.w;
      }
    }
  }
  unsigned short* Kv = K + (size_t)blockIdx.x*4096;
  #pragma unroll
  for(int j=0;j<8;j++){
    int m = mg*8 + j;
    u16x8 u;
    #pragma unroll
    for(int c=0;c<8;c++) u[c] = f2b(acc[j][c]);
    *(u16x8*)(Kv + m*64 + i0) = u;
  }
  if(mg==0){
    *(float4*)(XS + (size_t)v*64 + i0)     = xs0;
    *(float4*)(XS + (size_t)v*64 + i0 + 4) = xs1;
  }
}

// ---------------- MFMA split-K GEMM with register-prefetch double buffering ----------------

#define GBK 64

__global__ __launch_bounds__(256) void k_gemm(const unsigned short* __restrict__ A,
    const unsigned short* __restrict__ Bt, float* __restrict__ P,
    int rows, int Ktot, int Kc){
  __shared__ unsigned short As[128*72];
  __shared__ unsigned short Bs[64*72];
  int t = threadIdx.x;
  int lane = t & 63;
  int w = t >> 6;
  int row0 = blockIdx.x*128;
  int k0 = blockIdx.y*Kc;

  int srow  = t >> 3;        // 0..31
  int skseg = (t & 7) << 3;  // elem 0,8,...,56

  float4v acc[2][4];
  #pragma unroll
  for(int rt=0;rt<2;rt++)
    #pragma unroll
    for(int ct=0;ct<4;ct++)
      #pragma unroll
      for(int qq=0;qq<4;qq++) acc[rt][ct][qq]=0.f;

  int lrow = lane & 15;
  int lk   = (lane >> 4) << 3;

  short8 a_pf[4], b_pf[2];
  int T = Kc/GBK;

  // load tile 0 into regs
  {
    int kk = k0 + skseg;
    #pragma unroll
    for(int qq=0;qq<4;qq++){
      int gr = row0 + srow + 32*qq;
      short8 z = {0,0,0,0,0,0,0,0};
      a_pf[qq] = (gr<rows)? *(const short8*)(A + (size_t)gr*Ktot + kk) : z;
    }
    #pragma unroll
    for(int qq=0;qq<2;qq++){
      int o = srow + 32*qq;
      b_pf[qq] = *(const short8*)(Bt + (size_t)o*Ktot + kk);
    }
  }

  for(int tt=0; tt<T; tt++){
    __syncthreads();   // previous compute done before overwriting LDS
    #pragma unroll
    for(int qq=0;qq<4;qq++)
      *(short8*)(As + (srow + 32*qq)*72 + skseg) = a_pf[qq];
    #pragma unroll
    for(int qq=0;qq<2;qq++)
      *(short8*)(Bs + (srow + 32*qq)*72 + skseg) = b_pf[qq];
    __syncthreads();
    // prefetch next tile while computing this one
    if(tt+1 < T){
      int kk = k0 + (tt+1)*GBK + skseg;
      #pragma unroll
      for(int qq=0;qq<4;qq++){
        int gr = row0 + srow + 32*qq;
        short8 z = {0,0,0,0,0,0,0,0};
        a_pf[qq] = (gr<rows)? *(const short8*)(A + (size_t)gr*Ktot + kk) : z;
      }
      #pragma unroll
      for(int qq=0;qq<2;qq++){
        int o = srow + 32*qq;
        b_pf[qq] = *(const short8*)(Bt + (size_t)o*Ktot + kk);
      }
    }
    #pragma unroll
    for(int k32=0;k32<2;k32++){
      int kf = k32*32 + lk;
      short8 a0 = *(short8*)(As + (w*32      + lrow)*72 + kf);
      short8 a1 = *(short8*)(As + (w*32 + 16 + lrow)*72 + kf);
      #pragma unroll
      for(int ct=0;ct<4;ct++){
        short8 b = *(short8*)(Bs + (ct*16 + lrow)*72 + kf);
        acc[0][ct] = __builtin_amdgcn_mfma_f32_16x16x32_bf16(a0, b, acc[0][ct], 0,0,0);
        acc[1][ct] = __builtin_amdgcn_mfma_f32_16x16x32_bf16(a1, b, acc[1][ct], 0,0,0);
      }
    }
  }
  size_t base = (size_t)blockIdx.y*rows*64;
  int quad = lane >> 4;
  #pragma unroll
  for(int rt=0;rt<2;rt++){
    #pragma unroll
    for(int ct=0;ct<4;ct++){
      int c = ct*16 + lrow;
      #pragma unroll
      for(int reg=0;reg<4;reg++){
        int r = row0 + w*32 + rt*16 + quad*4 + reg;
        if(r < rows) P[base + (size_t)r*64 + c] = acc[rt][ct][reg];
      }
    }
  }
}

// ---------------- split reduction + epilogue (layer1 / fallback) ----------------

template<int CIN, int SPLIT>
__global__ __launch_bounds__(256) void k_reduce_ep(const float* __restrict__ P, int rows, int v0,
    const float* __restrict__ XS, const float* __restrict__ b2, const float* __restrict__ xprev,
    const float* __restrict__ root, const float* __restrict__ bias, const int* __restrict__ offs,
    float* __restrict__ out){
  int idx = blockIdx.x*256 + threadIdx.x;
  if(idx >= rows*16) return;
  int r = idx >> 4, og = (idx & 15) << 2;
  int v = v0 + r;

  float4 s = make_float4(0.f,0.f,0.f,0.f);
  #pragma unroll
  for(int z=0; z<SPLIT; z++){
    float4 p = *(const float4*)(P + ((size_t)z*rows + r)*64 + og);
    s.x += p.x; s.y += p.y; s.z += p.z; s.w += p.w;
  }
  #pragma unroll
  for(int i=0;i<CIN;i++){
    float xsv = XS[(size_t)v*64 + i];
    float4 b = *(const float4*)(b2 + i*64 + og);
    s.x += xsv*b.x; s.y += xsv*b.y; s.z += xsv*b.z; s.w += xsv*b.w;
  }
  float4 rt = make_float4(0.f,0.f,0.f,0.f);
  #pragma unroll
  for(int i=0;i<CIN;i++){
    float xv = xprev[(size_t)v*CIN + i];
    float4 wv = *(const float4*)(root + i*64 + og);
    rt.x += xv*wv.x; rt.y += xv*wv.y; rt.z += xv*wv.z; rt.w += xv*wv.w;
  }
  float c = (float)(offs[v+1]-offs[v]); c = fmaxf(c, 1.f);
  float inv = 1.f/c;
  float4 bi = *(const float4*)(bias + og);
  float4 o;
  o.x = fmaxf(s.x*inv + rt.x + bi.x, 0.f);
  o.y = fmaxf(s.y*inv + rt.y + bi.y, 0.f);
  o.z = fmaxf(s.z*inv + rt.z + bi.z, 0.f);
  o.w = fmaxf(s.w*inv + rt.w + bi.w, 0.f);
  *(float4*)(out + (size_t)v*64 + og) = o;
}

// ---------------- layer-2 reduction + epilogue + fused readout ----------------

template<int SPLIT>
__global__ __launch_bounds__(256) void k_red2_ro(const float* __restrict__ P, int rows,
    const float* __restrict__ XS, const float* __restrict__ b2, const float* __restrict__ x1,
    const float* __restrict__ root, const float* __restrict__ bias, const int* __restrict__ offs,
    const float* __restrict__ lw1, const float* __restrict__ lb1,
    const float* __restrict__ lw2, const float* __restrict__ lb2,
    float* __restrict__ out){
  __shared__ float row[16][68];
  __shared__ float hjs[16][8];
  int tid = threadIdx.x;
  int idx = blockIdx.x*256 + tid;
  int r = idx >> 4, og = (idx & 15) << 2;
  int n = tid >> 4;
  int nbase = blockIdx.x*16;
  int ninblk = rows - nbase; if(ninblk > 16) ninblk = 16;

  float4 o = make_float4(0.f,0.f,0.f,0.f);
  if(r < rows){
    float4 s = make_float4(0.f,0.f,0.f,0.f);
    #pragma unroll
    for(int z=0; z<SPLIT; z++){
      float4 p = *(const float4*)(P + ((size_t)z*rows + r)*64 + og);
      s.x += p.x; s.y += p.y; s.z += p.z; s.w += p.w;
    }
    #pragma unroll
    for(int i=0;i<64;i++){
      float xsv = XS[(size_t)r*64 + i];
      float4 b = *(const float4*)(b2 + i*64 + og);
      s.x += xsv*b.x; s.y += xsv*b.y; s.z += xsv*b.z; s.w += xsv*b.w;
    }
    float4 rt = make_float4(0.f,0.f,0.f,0.f);
    #pragma unroll
    for(int i=0;i<64;i++){
      float xv = x1[(size_t)r*64 + i];
      float4 wv = *(const float4*)(root + i*64 + og);
      rt.x += xv*wv.x; rt.y += xv*wv.y; rt.z += xv*wv.z; rt.w += xv*wv.w;
    }
    float c = (float)(offs[r+1]-offs[r]); c = fmaxf(c, 1.f);
    float inv = 1.f/c;
    float4 bi = *(const float4*)(bias + og);
    o.x = fmaxf(s.x*inv + rt.x + bi.x, 0.f);
    o.y = fmaxf(s.y*inv + rt.y + bi.y, 0.f);
    o.z = fmaxf(s.z*inv + rt.z + bi.z, 0.f);
    o.w = fmaxf(s.w*inv + rt.w + bi.w, 0.f);
  }
  *(float4*)&row[n][og] = o;
  __syncthreads();
  if(tid < 128){
    int n2 = tid >> 3, j = tid & 7;
    if(n2 < ninblk){
      float a = lb1[j];
      #pragma unroll
      for(int i=0;i<64;i++) a += row[n2][i]*lw1[i*8+j];
      hjs[n2][j] = fmaxf(a, 0.f)*lw2[j];
    }
  }
  __syncthreads();
  if(tid < 16 && tid < ninblk){
    float s = lb2[0];
    #pragma unroll
    for(int j=0;j<8;j++) s += hjs[tid][j];
    out[nbase + tid] = s;
  }
}

// ---------------- readout (fallback path only) ----------------

__global__ void k_readout(const float* __restrict__ x2, const float* __restrict__ lw1,
                          const float* __restrict__ lb1, const float* __restrict__ lw2,
                          const float* __restrict__ lb2, float* __restrict__ out){
  int v = blockIdx.x*256 + threadIdx.x;
  if(v >= NN) return;
  float accj[8];
  #pragma unroll
  for(int j=0;j<8;j++) accj[j] = lb1[j];
  const float* xr = x2 + (size_t)v*64;
  #pragma unroll 16
  for(int i=0;i<64;i++){
    float xv = xr[i];
    #pragma unroll
    for(int j=0;j<8;j++) accj[j] += xv*lw1[i*8+j];
  }
  float o = lb2[0];
  #pragma unroll
  for(int j=0;j<8;j++) o += fmaxf(accj[j],0.f)*lw2[j];
  out[v] = o;
}

// ---------------- host ----------------

extern "C" void kernel_launch(void* const* d_in, const int* in_sizes, int n_in,
                              void* d_out, int out_size, void* d_ws, size_t ws_size,
                              hipStream_t stream) {
  const float* x      = (const float*)d_in[0];
  const int*   ei     = (const int*)d_in[1];
  const float* ea     = (const float*)d_in[2];
  const float* nn1_w1 = (const float*)d_in[3];
  const float* nn1_b1 = (const float*)d_in[4];
  const float* nn1_w2 = (const float*)d_in[5];
  const float* nn1_b2 = (const float*)d_in[6];
  const float* root1  = (const float*)d_in[7];
  const float* bias1  = (const float*)d_in[8];
  const float* nn2_w1 = (const float*)d_in[9];
  const float* nn2_b1 = (const float*)d_in[10];
  const float* nn2_w2 = (const float*)d_in[11];
  const float* nn2_b2 = (const float*)d_in[12];
  const float* root2  = (const float*)d_in[13];
  const float* bias2  = (const float*)d_in[14];
  const float* lin1_w = (const float*)d_in[15];
  const float* lin1_b = (const float*)d_in[16];
  const float* lin2_w = (const float*)d_in[17];
  const float* lin2_b = (const float*)d_in[18];
  float* out = (float*)d_out;

  const int* srcIdx = ei;
  const int* dstIdx = ei + EE;

  char* w = (char*)d_ws;
  size_t off = 0;
  auto alloc = [&](size_t bytes)->void*{
    void* p = w + off;
    off = (off + bytes + 255) & ~(size_t)255;
    return p;
  };
  int*            cnt    = (int*)           alloc((size_t)NN*4);
  int*            offs   = (int*)           alloc((size_t)(NN+1)*4);
  int*            cursor = (int*)           alloc((size_t)NN*4);
  int*            elist  = (int*)           alloc((size_t)EE*4);
  float*          h1     = (float*)         alloc((size_t)EE*64*4);
  float*          h2     = (float*)         alloc((size_t)EE*64*4);
  float*          XS     = (float*)         alloc((size_t)NN*64*4);
  float*          x1     = (float*)         alloc((size_t)NN*64*4);
  unsigned short* Bt1    = (unsigned short*)alloc((size_t)64*1024*2);
  unsigned short* Bt2    = (unsigned short*)alloc((size_t)64*4096*2);
  size_t fixedBytes = off;
  size_t R = (ws_size > fixedBytes) ? (ws_size - fixedBytes) : 0;

  const int S1 = 4, S2 = 8;
  size_t needSingle = (size_t)NN*4096*2 + (size_t)S2*NN*64*4;  // K2 + P2 (dominant)
  bool single = (R >= needSingle + 4096);

  k_prep<<<34088, 256, 0, stream>>>(ea, nn1_w1, nn1_b1, h1, nn2_w1, nn2_b1, h2,
                                    nn1_w2, Bt1, nn2_w2, Bt2, cnt);
  k_hist   <<<(EE+255)/256, 256, 0, stream>>>(dstIdx, cnt);
  k_scan   <<<1, 1024, 0, stream>>>(cnt, offs, cursor);
  k_scatter<<<(EE+255)/256, 256, 0, stream>>>(dstIdx, cursor, elist);

  if(single){
    unsigned short* Kbuf = (unsigned short*)(w + off);
    float* P = (float*)(w + off + (size_t)NN*4096*2);

    // ---------- layer 1 ----------
    k_accK1<<<NN, 64, 0, stream>>>(x, srcIdx, offs, elist, h1, Kbuf, XS, 0);
    {
      dim3 g((NN+127)/128, S1);
      k_gemm<<<g, 256, 0, stream>>>(Kbuf, Bt1, P, NN, 1024, 1024/S1);
    }
    k_reduce_ep<16,S1><<<(NN*16+255)/256, 256, 0, stream>>>(P, NN, 0, XS, nn1_b2, x,
                                                             root1, bias1, offs, x1);
    // ---------- layer 2 + fused readout ----------
    k_accK2<<<NN, 64, 0, stream>>>(x1, srcIdx, offs, elist, h2, Kbuf, XS, 0);
    {
      dim3 g((NN+127)/128, S2);
      k_gemm<<<g, 256, 0, stream>>>(Kbuf, Bt2, P, NN, 4096, 4096/S2);
    }
    k_red2_ro<S2><<<(NN+15)/16, 256, 0, stream>>>(P, NN, XS, nn2_b2, x1, root2, bias2, offs,
                                                   lin1_w, lin1_b, lin2_w, lin2_b, out);
  } else {
    float* x2b = (float*)alloc((size_t)NN*64*4);
    R = (ws_size > off) ? (ws_size - off) : 0;
    long long C2 = (long long)(R / (4096*2 + S2*64*4));
    long long C1 = (long long)(R / (1024*2 + S1*64*4));
    if(C2 > NN) C2 = NN; if(C1 > NN) C1 = NN;
    if(C2 < 128) C2 = 128; if(C1 < 128) C1 = 128;
    unsigned short* Kbuf = (unsigned short*)(w + off);
    {
      float* P = (float*)(w + off + (size_t)C1*1024*2);
      for(long long v0=0; v0<NN; v0+=C1){
        int rows = (int)((NN - v0 < C1) ? (NN - v0) : C1);
        k_accK1<<<rows, 64, 0, stream>>>(x, srcIdx, offs, elist, h1, Kbuf, XS, (int)v0);
        dim3 g((rows+127)/128, S1);
        k_gemm<<<g, 256, 0, stream>>>(Kbuf, Bt1, P, rows, 1024, 1024/S1);
        k_reduce_ep<16,S1><<<(rows*16+255)/256, 256, 0, stream>>>(P, rows, (int)v0, XS, nn1_b2, x,
                                                                   root1, bias1, offs, x1);
      }
    }
    {
      float* P = (float*)(w + off + (size_t)C2*4096*2);
      for(long long v0=0; v0<NN; v0+=C2){
        int rows = (int)((NN - v0 < C2) ? (NN - v0) : C2);
        k_accK2<<<rows, 64, 0, stream>>>(x1, srcIdx, offs, elist, h2, Kbuf, XS, (int)v0);
        dim3 g((rows+127)/128, S2);
        k_gemm<<<g, 256, 0, stream>>>(Kbuf, Bt2, P, rows, 4096, 4096/S2);
        k_reduce_ep<64,S2><<<(rows*16+255)/256, 256, 0, stream>>>(P, rows, (int)v0, XS, nn2_b2, x1,
                                                                   root2, bias2, offs, x2b);
      }
    }
    k_readout<<<(NN+255)/256, 256, 0, stream>>>(x2b, lin1_w, lin1_b, lin2_w, lin2_b, out);
  }
}